// Round 11
// baseline (1590.790 us; speedup 1.0000x reference)
//
#include <hip/hip_runtime.h>
#include <hip/hip_bf16.h>

typedef unsigned int u32;
typedef unsigned short u16;

#define DF __device__ __forceinline__

DF float bf2f(u16 v){ u32 t = ((u32)v)<<16; return __builtin_bit_cast(float, t); }
DF u16 f2bf(float f){
  u32 t = __builtin_bit_cast(u32, f);
  t += 0x7fffu + ((t>>16)&1u);
  return (u16)(t>>16);
}
DF float lo16(u32 p){ return __builtin_bit_cast(float, p<<16); }
DF float hi16(u32 p){ return __builtin_bit_cast(float, p & 0xffff0000u); }
DF u32 pack2(float a, float b){ return (u32)f2bf(a) | (((u32)f2bf(b))<<16); }
DF float gelu(float x){ return 0.5f*x*(1.0f+erff(x*0.70710678118654752f)); }

// dot2: acc += a.lo*b.lo + a.hi*b.hi (bf16 pairs) via HW v_dot2_f32_bf16.
DF float dot2bf(u32 a, u32 b, float c){
  float d;
  asm("v_dot2_f32_bf16 %0, %1, %2, %3" : "=v"(d) : "v"(a), "v"(b), "v"(c));
  return d;
}
DF u32 c4(const uint4 v, int j){ return j==0?v.x : j==1?v.y : j==2?v.z : v.w; }

// ---------------------------------------------------------------------------
// K0: pack qkv/proj weights for dot2 (front of d_out, consumed by attn).
// ---------------------------------------------------------------------------
__global__ void wprep_k(const float* __restrict__ qkvw, const float* __restrict__ projw,
                        u32* __restrict__ w8q, u32* __restrict__ w8p)
{
  int e = blockIdx.x*256 + threadIdx.x;
  if (e < 13824){
    int og = e/384, r = e - og*384, cp = r>>3, k = r&7;
    int o = og*8 + k;
    w8q[e] = pack2(qkvw[o*96 + 2*cp], qkvw[o*96 + 2*cp + 1]);
  } else if (e < 18432){
    int r2 = e - 13824;
    int og = r2/384, r = r2 - og*384, cp = r>>3, k = r&7;
    int o = og*8 + k;
    w8p[r2] = pack2(projw[o*96 + 2*cp], projw[o*96 + 2*cp + 1]);
  }
}

// ---------------------------------------------------------------------------
// K0b: pack conv weights for dot2 into ws tail: [conv][tap][c2(48)][o(96)].
// ---------------------------------------------------------------------------
__global__ void wprep_cv(const float* __restrict__ c1w, const float* __restrict__ c2w,
                         u32* __restrict__ wcv)
{
  int e = blockIdx.x*256 + threadIdx.x;
  if (e >= 82944) return;
  int conv = e / 41472, r = e - conv*41472;
  int tap = r / 4608, r2 = r - tap*4608;
  int c2 = r2 / 96, o = r2 - c2*96;
  const float* s = conv ? c2w : c1w;
  wcv[e] = pack2(s[(o*96 + 2*c2)*9 + tap], s[(o*96 + 2*c2 + 1)*9 + tap]);
}

// ---------------------------------------------------------------------------
// K1: fused windowed attention (structure unchanged from R10; 3 blocks/CU).
// ---------------------------------------------------------------------------
__global__ __launch_bounds__(256,3) void attn_k(
    const float* __restrict__ x, const float* __restrict__ ndwi,
    const float* __restrict__ n1g, const float* __restrict__ n1b,
    const u32* __restrict__ w8q, const float* __restrict__ qb,
    const u32* __restrict__ w8p, const float* __restrict__ pb,
    const float* __restrict__ rpbt, u16* __restrict__ x1o)
{
  __shared__ u32 xp[49*49];
  __shared__ u32 qp[49*49];
  __shared__ u32 kp[49*49];
  __shared__ u16 vpT[96*50];
  __shared__ float rpb[8*169];
  __shared__ float mw[49];
  const int tid = threadIdx.x;
  const int blk = blockIdx.x;
  const int b = blk >> 10, wy = (blk>>5)&31, wx = blk&31;
  const int wv_ = __builtin_amdgcn_readfirstlane(tid >> 6);
  const int ln  = tid & 63;
  const int lnc = ln < 49 ? ln : 48;

  for (int i = tid; i < 1352; i += 256){
    int h = i/169, idx = i - h*169;
    rpb[i] = rpbt[idx*8 + h];
  }
  for (int i = tid; i < 96; i += 256) vpT[i*50 + 49] = 0;

  // LN1 straight from global: 4 lanes per token
  if (tid < 196){
    const int t = tid >> 2, p = tid & 3;
    const int ty = t/7, tx = t - (t/7)*7;
    int sy = wy*7 + ty - 3; if (sy < 0) sy += 224;
    int sx = wx*7 + tx - 3; if (sx < 0) sx += 224;
    const size_t rowb = ((size_t)((b*224 + sy)*224 + sx))*96;
    const float* xr = x + rowb + p*24;
    float c[24];
    #pragma unroll
    for (int q = 0; q < 6; q++){
      float4 v = ((const float4*)xr)[q];
      c[q*4+0]=v.x; c[q*4+1]=v.y; c[q*4+2]=v.z; c[q*4+3]=v.w;
    }
    if (p == 0) mw[t] = ndwi[(size_t)b*50176 + sy*224 + sx];
    float s = 0.f, s2 = 0.f;
    #pragma unroll
    for (int j = 0; j < 24; j++){ s += c[j]; s2 += c[j]*c[j]; }
    s  += __shfl_xor(s, 1);  s  += __shfl_xor(s, 2);
    s2 += __shfl_xor(s2, 1); s2 += __shfl_xor(s2, 2);
    float m = s*(1.f/96.f);
    float rs = rsqrtf(s2*(1.f/96.f) - m*m + 1e-5f);
    #pragma unroll
    for (int jj = 0; jj < 12; jj++){
      float a = (c[2*jj]  -m)*rs*n1g[p*24+2*jj]   + n1b[p*24+2*jj];
      float d = (c[2*jj+1]-m)*rs*n1g[p*24+2*jj+1] + n1b[p*24+2*jj+1];
      xp[t*49 + p*12 + jj] = pack2(a, d);
    }
  }
  __syncthreads();

  // QKV: wave handles 9 output-groups of 8; lane = token
  for (int ogi = 0; ogi < 9; ogi++){
    const int og = wv_*9 + ogi;
    const int o0 = og*8;
    const u32* wrow = w8q + og*384;
    float acc[8];
    #pragma unroll
    for (int k = 0; k < 8; k++) acc[k] = qb[o0+k];
    #pragma unroll 4
    for (int cp = 0; cp < 48; cp++){
      u32 xv = xp[lnc*49 + cp];
      uint4 wa = *(const uint4*)(wrow + cp*8);
      uint4 wb = *(const uint4*)(wrow + cp*8 + 4);
      acc[0] = dot2bf(xv, wa.x, acc[0]); acc[1] = dot2bf(xv, wa.y, acc[1]);
      acc[2] = dot2bf(xv, wa.z, acc[2]); acc[3] = dot2bf(xv, wa.w, acc[3]);
      acc[4] = dot2bf(xv, wb.x, acc[4]); acc[5] = dot2bf(xv, wb.y, acc[5]);
      acc[6] = dot2bf(xv, wb.z, acc[6]); acc[7] = dot2bf(xv, wb.w, acc[7]);
    }
    if (ln < 49){
      if (og < 12){
        const float S = 0.28867513459481287f;
        #pragma unroll
        for (int m = 0; m < 4; m++) qp[ln*49 + og*4 + m] = pack2(acc[2*m]*S, acc[2*m+1]*S);
      } else if (og < 24){
        #pragma unroll
        for (int m = 0; m < 4; m++) kp[ln*49 + (og-12)*4 + m] = pack2(acc[2*m], acc[2*m+1]);
      } else {
        const int o0v = (og-24)*8;
        #pragma unroll
        for (int k = 0; k < 8; k++) vpT[(o0v+k)*50 + ln] = f2bf(acc[k]);
      }
    }
  }
  __syncthreads();

  // attention: task = (head, query row)
  for (int task = tid; task < 392; task += 256){
    int h = task/49, i = task - (task/49)*49;
    int iy = i/7, ix = i - (i/7)*7;
    u32 qv[6];
    #pragma unroll
    for (int e = 0; e < 6; e++) qv[e] = qp[i*49 + h*6 + e];
    const float* rb = &rpb[h*169 + (iy+6)*13 + (ix+6)];
    float s[49]; float mx = -1e30f;
    float mi = mw[i];
    int j = 0;
    #pragma unroll
    for (int jy = 0; jy < 7; jy++)
    #pragma unroll
    for (int jx = 0; jx < 7; jx++, j++){
      const u32* kr = &kp[j*49 + h*6];
      float a = rb[-(jy*13+jx)];
      a = dot2bf(qv[0], kr[0], a); a = dot2bf(qv[1], kr[1], a);
      a = dot2bf(qv[2], kr[2], a); a = dot2bf(qv[3], kr[3], a);
      a = dot2bf(qv[4], kr[4], a); a = dot2bf(qv[5], kr[5], a);
      a = (mi != mw[j]) ? a - 100.f : a;
      s[j] = a; mx = fmaxf(mx, a);
    }
    float l = 0.f;
    #pragma unroll
    for (int jj = 0; jj < 49; jj++){ float p = __expf(s[jj]-mx); s[jj] = p; l += p; }
    float rl = 1.f/l;
    u32 pp[25];
    #pragma unroll
    for (int e = 0; e < 24; e++)
      pp[e] = (__builtin_bit_cast(u32, s[2*e]) >> 16)
            | (__builtin_bit_cast(u32, s[2*e+1]) & 0xffff0000u);
    pp[24] = __builtin_bit_cast(u32, s[48]) >> 16;
    float o[12];
    #pragma unroll
    for (int d = 0; d < 12; d++){
      const u32* vr = (const u32*)(vpT + (h*12+d)*50);
      float od = 0.f;
      #pragma unroll
      for (int e = 0; e < 25; e++) od = dot2bf(pp[e], vr[e], od);
      o[d] = od*rl;
    }
    #pragma unroll
    for (int m = 0; m < 6; m++) xp[i*49 + h*6 + m] = pack2(o[2*m], o[2*m+1]);
  }
  __syncthreads();

  // proj -> bf16 pairs into qp (dead after QK^T)
  for (int ogi = 0; ogi < 3; ogi++){
    const int og = wv_*3 + ogi;
    const int o0 = og*8;
    const u32* wrow = w8p + og*384;
    float acc[8];
    #pragma unroll
    for (int k = 0; k < 8; k++) acc[k] = pb[o0+k];
    #pragma unroll 4
    for (int cp = 0; cp < 48; cp++){
      u32 xv = xp[lnc*49 + cp];
      uint4 wa = *(const uint4*)(wrow + cp*8);
      uint4 wb = *(const uint4*)(wrow + cp*8 + 4);
      acc[0] = dot2bf(xv, wa.x, acc[0]); acc[1] = dot2bf(xv, wa.y, acc[1]);
      acc[2] = dot2bf(xv, wa.z, acc[2]); acc[3] = dot2bf(xv, wa.w, acc[3]);
      acc[4] = dot2bf(xv, wb.x, acc[4]); acc[5] = dot2bf(xv, wb.y, acc[5]);
      acc[6] = dot2bf(xv, wb.z, acc[6]); acc[7] = dot2bf(xv, wb.w, acc[7]);
    }
    if (ln < 49){
      #pragma unroll
      for (int m = 0; m < 4; m++) qp[ln*49 + og*4 + m] = pack2(acc[2*m], acc[2*m+1]);
    }
  }
  __syncthreads();

  // write: reverse roll (-4) + residual
  for (int e = tid; e < 588; e += 256){
    int t = e/12, g = e - (e/12)*12;
    int ty = t/7, tx = t - (t/7)*7;
    int dy = wy*7 + ty - 4; if (dy < 0) dy += 224;
    int dx = wx*7 + tx - 4; if (dx < 0) dx += 224;
    size_t base = ((size_t)((b*224+dy)*224+dx))*96 + g*8;
    float4 r0 = *(const float4*)(x + base);
    float4 r1 = *(const float4*)(x + base + 4);
    const u32* pr = &qp[t*49 + g*4];
    uint4 ov;
    ov.x = pack2(lo16(pr[0])+r0.x, hi16(pr[0])+r0.y);
    ov.y = pack2(lo16(pr[1])+r0.z, hi16(pr[1])+r0.w);
    ov.z = pack2(lo16(pr[2])+r1.x, hi16(pr[2])+r1.y);
    ov.w = pack2(lo16(pr[3])+r1.z, hi16(pr[3])+r1.w);
    *(uint4*)(x1o + base) = ov;
  }
}

// ---------------------------------------------------------------------------
// K2: fused LN2 + MLP + residual, b128-transposed edition.
// xtT[cp][tok], hlT[hp][tok] (tokens contiguous -> ds_read_b128 = 4 tokens);
// w1l/w2l rows padded to 52 dwords (16B-aligned + hg-distinct bank quads).
// LDS 66KB -> 2 blocks/CU.
// ---------------------------------------------------------------------------
__global__ __launch_bounds__(256,2) void mlp_k(
    const u16* __restrict__ x1, const float* __restrict__ w1, const float* __restrict__ b1,
    const float* __restrict__ w2, const float* __restrict__ b2,
    const float* __restrict__ g2, const float* __restrict__ bb2,
    float* __restrict__ x2o)
{
  __shared__ __align__(16) u32 xtT[48*64];   // [cp][tok]
  __shared__ __align__(16) u32 hlT[48*64];   // [hp][tok]
  __shared__ __align__(16) u32 w1l[96*52];   // [hh][cp], row stride 52
  __shared__ __align__(16) u32 w2l[96*52];   // [oc][hp], row stride 52
  __shared__ float b1s[384];
  const int tid = threadIdx.x;
  const size_t t0 = (size_t)blockIdx.x * 64;

  for (int i = tid; i < 384; i += 256) b1s[i] = b1[i];

  // LN2: 4 lanes per token -> xtT transposed
  {
    const int t = tid >> 2, p = tid & 3;
    const u16* xr = x1 + (t0 + t)*96 + p*24;
    float c[24];
    #pragma unroll
    for (int q = 0; q < 3; q++){
      uint4 v = ((const uint4*)xr)[q];
      c[q*8+0]=lo16(v.x); c[q*8+1]=hi16(v.x);
      c[q*8+2]=lo16(v.y); c[q*8+3]=hi16(v.y);
      c[q*8+4]=lo16(v.z); c[q*8+5]=hi16(v.z);
      c[q*8+6]=lo16(v.w); c[q*8+7]=hi16(v.w);
    }
    float s = 0.f, s2 = 0.f;
    #pragma unroll
    for (int j = 0; j < 24; j++){ s += c[j]; s2 += c[j]*c[j]; }
    s  += __shfl_xor(s, 1);  s  += __shfl_xor(s, 2);
    s2 += __shfl_xor(s2, 1); s2 += __shfl_xor(s2, 2);
    float m = s*(1.f/96.f);
    float rs = rsqrtf(s2*(1.f/96.f) - m*m + 1e-5f);
    #pragma unroll
    for (int jj = 0; jj < 12; jj++){
      float a = (c[2*jj]  -m)*rs*g2[p*24+2*jj]   + bb2[p*24+2*jj];
      float d = (c[2*jj+1]-m)*rs*g2[p*24+2*jj+1] + bb2[p*24+2*jj+1];
      xtT[(p*12+jj)*64 + t] = pack2(a, d);
    }
  }

  const int ttg = tid & 15;     // token group: tokens ttg*4+0..3
  const int hg  = tid >> 4;     // hidden/out channel group: hg*6+0..5
  float oacc[4][6];
  #pragma unroll
  for (int i = 0; i < 4; i++)
    #pragma unroll
    for (int k = 0; k < 6; k++) oacc[i][k] = 0.f;

  for (int q = 0; q < 4; q++){
    const int h0 = q*96;
    __syncthreads();
    for (int e = tid; e < 4608; e += 256){
      int r = e/48, cpp = e - (e/48)*48;
      float2 a1 = *(const float2*)(w1 + (size_t)(h0+r)*96 + 2*cpp);
      w1l[r*52+cpp] = pack2(a1.x, a1.y);
      float2 a2 = *(const float2*)(w2 + (size_t)r*384 + h0 + 2*cpp);
      w2l[r*52+cpp] = pack2(a2.x, a2.y);
    }
    __syncthreads();
    // phase A: h = xn @ w1^T  (4 tok x 6 h per thread)
    float a[4][6];
    #pragma unroll
    for (int i = 0; i < 4; i++)
      #pragma unroll
      for (int k = 0; k < 6; k++) a[i][k] = b1s[h0 + hg*6 + k];
    for (int cb = 0; cb < 12; cb++){
      uint4 xv[4], wv[6];
      #pragma unroll
      for (int j = 0; j < 4; j++) xv[j] = *(const uint4*)&xtT[(cb*4+j)*64 + ttg*4];
      #pragma unroll
      for (int k = 0; k < 6; k++) wv[k] = *(const uint4*)&w1l[(hg*6+k)*52 + cb*4];
      #pragma unroll
      for (int j = 0; j < 4; j++){
        const u32 v0 = xv[j].x, v1 = xv[j].y, v2 = xv[j].z, v3 = xv[j].w;
        #pragma unroll
        for (int k = 0; k < 6; k++){
          const u32 w = c4(wv[k], j);
          a[0][k] = dot2bf(v0, w, a[0][k]);
          a[1][k] = dot2bf(v1, w, a[1][k]);
          a[2][k] = dot2bf(v2, w, a[2][k]);
          a[3][k] = dot2bf(v3, w, a[3][k]);
        }
      }
    }
    // gelu -> hlT transposed
    #pragma unroll
    for (int i = 0; i < 4; i++)
      #pragma unroll
      for (int p3 = 0; p3 < 3; p3++)
        hlT[(hg*3+p3)*64 + (ttg*4+i)] = pack2(gelu(a[i][2*p3]), gelu(a[i][2*p3+1]));
    __syncthreads();
    // phase B: out += gelu(h) @ w2^T
    for (int hb = 0; hb < 12; hb++){
      uint4 hv[4], wv[6];
      #pragma unroll
      for (int j = 0; j < 4; j++) hv[j] = *(const uint4*)&hlT[(hb*4+j)*64 + ttg*4];
      #pragma unroll
      for (int k = 0; k < 6; k++) wv[k] = *(const uint4*)&w2l[(hg*6+k)*52 + hb*4];
      #pragma unroll
      for (int j = 0; j < 4; j++){
        const u32 v0 = hv[j].x, v1 = hv[j].y, v2 = hv[j].z, v3 = hv[j].w;
        #pragma unroll
        for (int k = 0; k < 6; k++){
          const u32 w = c4(wv[k], j);
          oacc[0][k] = dot2bf(v0, w, oacc[0][k]);
          oacc[1][k] = dot2bf(v1, w, oacc[1][k]);
          oacc[2][k] = dot2bf(v2, w, oacc[2][k]);
          oacc[3][k] = dot2bf(v3, w, oacc[3][k]);
        }
      }
    }
  }

  // epilogue: x2 = x1 + out + b2  (f32 to d_out)
  const int oc0 = hg*6;
  float b2v[6];
  #pragma unroll
  for (int k = 0; k < 6; k++) b2v[k] = b2[oc0+k];
  #pragma unroll
  for (int i = 0; i < 4; i++){
    size_t tok = t0 + ttg*4 + i;
    const u32* rr = (const u32*)(x1 + tok*96 + oc0);
    float* orow = x2o + tok*96 + oc0;
    #pragma unroll
    for (int p3 = 0; p3 < 3; p3++){
      u32 rv = rr[p3];
      float2 st;
      st.x = lo16(rv) + oacc[i][2*p3]   + b2v[2*p3];
      st.y = hi16(rv) + oacc[i][2*p3+1] + b2v[2*p3+1];
      *(float2*)(orow + 2*p3) = st;
    }
  }
}

// ---------------------------------------------------------------------------
// K3a: per-pixel LN3 + 3x3 conv (dil 1) + bias + BN + GELU (unchanged).
// ---------------------------------------------------------------------------
__global__ __launch_bounds__(256,2) void conv1_k(
    const float* __restrict__ src, const u32* __restrict__ wpk,
    const float* __restrict__ wOIHW,
    const float* __restrict__ cb, const float* __restrict__ bng, const float* __restrict__ bnb,
    const float* __restrict__ bnm, const float* __restrict__ bnv,
    const float* __restrict__ g3, const float* __restrict__ b3,
    u16* __restrict__ dst)
{
  constexpr int DIL = 1, SY = 10, SX = 18;
  __shared__ u32 intile[SY*SX*49];
  __shared__ __align__(16) u32 wsl[4608];
  const int tid = threadIdx.x;
  const int bx = blockIdx.x*16, by = blockIdx.y*8, b = blockIdx.z;
  const int gy0 = by - DIL, gx0 = bx - DIL;
  for (int e = tid; e < SY*SX*48; e += 256){
    int p = e/48, c2 = e - (e/48)*48;
    int y = p/SX, xx = p - (p/SX)*SX;
    int gy = gy0+y, gx = gx0+xx;
    u32 v = 0;
    if (gy >= 0 && gy < 224 && gx >= 0 && gx < 224){
      float2 rd = *(const float2*)(src + ((size_t)((b*224+gy)*224+gx))*96 + c2*2);
      v = pack2(rd.x, rd.y);
    }
    intile[p*49 + c2] = v;
  }
  __syncthreads();
  for (int p = tid; p < SY*SX; p += 256){
    int y = p/SX, xx = p - (p/SX)*SX;
    int gy = gy0+y, gx = gx0+xx;
    if (gy >= 0 && gy < 224 && gx >= 0 && gx < 224){
      u32* row = &intile[p*49];
      float m = 0.f;
      #pragma unroll
      for (int c2 = 0; c2 < 48; c2++){ u32 v = row[c2]; m += lo16(v)+hi16(v); }
      m *= (1.f/96.f);
      float var = 0.f;
      #pragma unroll
      for (int c2 = 0; c2 < 48; c2++){
        u32 v = row[c2];
        float d0 = lo16(v)-m, d1 = hi16(v)-m;
        var += d0*d0 + d1*d1;
      }
      float rs = rsqrtf(var*(1.f/96.f)+1e-5f);
      #pragma unroll
      for (int c2 = 0; c2 < 48; c2++){
        u32 v = row[c2];
        float2 gg = *(const float2*)(g3 + 2*c2);
        float2 bb = *(const float2*)(b3 + 2*c2);
        row[c2] = pack2((lo16(v)-m)*rs*gg.x+bb.x,
                        (hi16(v)-m)*rs*gg.y+bb.y);
      }
    }
  }
  const int pxg = tid & 31, og = tid >> 5;
  const int px8 = pxg & 15, py8 = pxg >> 4;
  const int o0 = og*12;
  float acc[4][12];
  #pragma unroll
  for (int a = 0; a < 4; a++)
    #pragma unroll
    for (int j = 0; j < 12; j++) acc[a][j] = 0.f;

  for (int tap = 0; tap < 9; tap++){
    const int ky = tap/3, kx = tap - (tap/3)*3;
    __syncthreads();
    if (wpk){
      const u32* wsrc = wpk + tap*4608;
      for (int e = tid; e < 4608; e += 256) wsl[e] = wsrc[e];
    } else {
      for (int e = tid; e < 4608; e += 256){
        int c2 = e/96, o = e - (e/96)*96;
        wsl[e] = pack2(wOIHW[(o*96 + 2*c2)*9 + tap], wOIHW[(o*96 + 2*c2 + 1)*9 + tap]);
      }
    }
    __syncthreads();
    for (int c2 = 0; c2 < 48; c2++){
      u32 iv[4];
      #pragma unroll
      for (int a = 0; a < 4; a++)
        iv[a] = intile[((py8+2*a+ky*DIL)*SX + (px8+kx*DIL))*49 + c2];
      const u32* wr = &wsl[c2*96 + o0];
      uint4 wA = *(const uint4*)(wr);
      uint4 wB = *(const uint4*)(wr+4);
      uint4 wC = *(const uint4*)(wr+8);
      #pragma unroll
      for (int a = 0; a < 4; a++){
        u32 v = iv[a];
        acc[a][0]  = dot2bf(v, wA.x, acc[a][0]);
        acc[a][1]  = dot2bf(v, wA.y, acc[a][1]);
        acc[a][2]  = dot2bf(v, wA.z, acc[a][2]);
        acc[a][3]  = dot2bf(v, wA.w, acc[a][3]);
        acc[a][4]  = dot2bf(v, wB.x, acc[a][4]);
        acc[a][5]  = dot2bf(v, wB.y, acc[a][5]);
        acc[a][6]  = dot2bf(v, wB.z, acc[a][6]);
        acc[a][7]  = dot2bf(v, wB.w, acc[a][7]);
        acc[a][8]  = dot2bf(v, wC.x, acc[a][8]);
        acc[a][9]  = dot2bf(v, wC.y, acc[a][9]);
        acc[a][10] = dot2bf(v, wC.z, acc[a][10]);
        acc[a][11] = dot2bf(v, wC.w, acc[a][11]);
      }
    }
  }
  float sc[12], mm[12], bb[12], cbv[12];
  #pragma unroll
  for (int j = 0; j < 12; j++){
    sc[j] = bng[o0+j]*rsqrtf(bnv[o0+j]+1e-5f);
    mm[j] = bnm[o0+j]; bb[j] = bnb[o0+j]; cbv[j] = cb[o0+j];
  }
  #pragma unroll
  for (int a = 0; a < 4; a++){
    int gy = by + py8 + 2*a, gx = bx + px8;
    size_t base = ((size_t)((b*224+gy)*224+gx))*96 + o0;
    #pragma unroll
    for (int d = 0; d < 6; d++){
      float t0 = (acc[a][2*d]   + cbv[2*d]   - mm[2*d])  *sc[2*d]   + bb[2*d];
      float t1 = (acc[a][2*d+1] + cbv[2*d+1] - mm[2*d+1])*sc[2*d+1] + bb[2*d+1];
      *(u32*)(dst + base + 2*d) = pack2(gelu(t0), gelu(t1));
    }
  }
}

// ---------------------------------------------------------------------------
// K3b: 3x3 conv (dil 2) + bias + BN + GELU + residual(x2) (unchanged).
// ---------------------------------------------------------------------------
__global__ __launch_bounds__(256,2) void conv2_k(
    const u16* __restrict__ src, const u32* __restrict__ wpk,
    const float* __restrict__ wOIHW,
    const float* __restrict__ cb, const float* __restrict__ bng, const float* __restrict__ bnb,
    const float* __restrict__ bnm, const float* __restrict__ bnv,
    const float* resid, float* dst)
{
  constexpr int DIL = 2, SY = 12, SX = 20;
  __shared__ u32 intile[SY*SX*49];
  __shared__ __align__(16) u32 wsl[4608];
  const int tid = threadIdx.x;
  const int bx = blockIdx.x*16, by = blockIdx.y*8, b = blockIdx.z;
  const int gy0 = by - DIL, gx0 = bx - DIL;
  for (int e = tid; e < SY*SX*48; e += 256){
    int p = e/48, c2 = e - (e/48)*48;
    int y = p/SX, xx = p - (p/SX)*SX;
    int gy = gy0+y, gx = gx0+xx;
    u32 v = 0;
    if (gy >= 0 && gy < 224 && gx >= 0 && gx < 224)
      v = *(const u32*)(src + ((size_t)((b*224+gy)*224+gx))*96 + c2*2);
    intile[p*49 + c2] = v;
  }
  const int pxg = tid & 31, og = tid >> 5;
  const int px8 = pxg & 15, py8 = pxg >> 4;
  const int o0 = og*12;
  float acc[4][12];
  #pragma unroll
  for (int a = 0; a < 4; a++)
    #pragma unroll
    for (int j = 0; j < 12; j++) acc[a][j] = 0.f;

  for (int tap = 0; tap < 9; tap++){
    const int ky = tap/3, kx = tap - (tap/3)*3;
    __syncthreads();
    if (wpk){
      const u32* wsrc = wpk + tap*4608;
      for (int e = tid; e < 4608; e += 256) wsl[e] = wsrc[e];
    } else {
      for (int e = tid; e < 4608; e += 256){
        int c2 = e/96, o = e - (e/96)*96;
        wsl[e] = pack2(wOIHW[(o*96 + 2*c2)*9 + tap], wOIHW[(o*96 + 2*c2 + 1)*9 + tap]);
      }
    }
    __syncthreads();
    for (int c2 = 0; c2 < 48; c2++){
      u32 iv[4];
      #pragma unroll
      for (int a = 0; a < 4; a++)
        iv[a] = intile[((py8+2*a+ky*DIL)*SX + (px8+kx*DIL))*49 + c2];
      const u32* wr = &wsl[c2*96 + o0];
      uint4 wA = *(const uint4*)(wr);
      uint4 wB = *(const uint4*)(wr+4);
      uint4 wC = *(const uint4*)(wr+8);
      #pragma unroll
      for (int a = 0; a < 4; a++){
        u32 v = iv[a];
        acc[a][0]  = dot2bf(v, wA.x, acc[a][0]);
        acc[a][1]  = dot2bf(v, wA.y, acc[a][1]);
        acc[a][2]  = dot2bf(v, wA.z, acc[a][2]);
        acc[a][3]  = dot2bf(v, wA.w, acc[a][3]);
        acc[a][4]  = dot2bf(v, wB.x, acc[a][4]);
        acc[a][5]  = dot2bf(v, wB.y, acc[a][5]);
        acc[a][6]  = dot2bf(v, wB.z, acc[a][6]);
        acc[a][7]  = dot2bf(v, wB.w, acc[a][7]);
        acc[a][8]  = dot2bf(v, wC.x, acc[a][8]);
        acc[a][9]  = dot2bf(v, wC.y, acc[a][9]);
        acc[a][10] = dot2bf(v, wC.z, acc[a][10]);
        acc[a][11] = dot2bf(v, wC.w, acc[a][11]);
      }
    }
  }
  float sc[12], mm[12], bb[12], cbv[12];
  #pragma unroll
  for (int j = 0; j < 12; j++){
    sc[j] = bng[o0+j]*rsqrtf(bnv[o0+j]+1e-5f);
    mm[j] = bnm[o0+j]; bb[j] = bnb[o0+j]; cbv[j] = cb[o0+j];
  }
  #pragma unroll
  for (int a = 0; a < 4; a++){
    int gy = by + py8 + 2*a, gx = bx + px8;
    size_t base = ((size_t)((b*224+gy)*224+gx))*96 + o0;
    float4 r0 = *(const float4*)(resid + base);
    float4 r1 = *(const float4*)(resid + base + 4);
    float4 r2 = *(const float4*)(resid + base + 8);
    float ov[12];
    #pragma unroll
    for (int j = 0; j < 12; j++){
      float t = (acc[a][j] + cbv[j] - mm[j])*sc[j] + bb[j];
      ov[j] = gelu(t);
    }
    float4 s0, s1, s2;
    s0.x = ov[0]+r0.x;  s0.y = ov[1]+r0.y;  s0.z = ov[2]+r0.z;  s0.w = ov[3]+r0.w;
    s1.x = ov[4]+r1.x;  s1.y = ov[5]+r1.y;  s1.z = ov[6]+r1.z;  s1.w = ov[7]+r1.w;
    s2.x = ov[8]+r2.x;  s2.y = ov[9]+r2.y;  s2.z = ov[10]+r2.z; s2.w = ov[11]+r2.w;
    *(float4*)(dst + base)     = s0;
    *(float4*)(dst + base + 4) = s1;
    *(float4*)(dst + base + 8) = s2;
  }
}

// ---------------------------------------------------------------------------
extern "C" void kernel_launch(void* const* d_in, const int* in_sizes, int n_in,
                              void* d_out, int out_size, void* d_ws, size_t ws_size,
                              hipStream_t stream)
{
  const float* x    = (const float*)d_in[0];
  const float* ndwi = (const float*)d_in[1];
  const float* n1g  = (const float*)d_in[2];
  const float* n1b  = (const float*)d_in[3];
  const float* qkvw = (const float*)d_in[4];
  const float* qkvb = (const float*)d_in[5];
  const float* projw= (const float*)d_in[6];
  const float* projb= (const float*)d_in[7];
  const float* rpbt = (const float*)d_in[8];
  const float* n2g  = (const float*)d_in[9];
  const float* n2b  = (const float*)d_in[10];
  const float* w1   = (const float*)d_in[11];
  const float* b1   = (const float*)d_in[12];
  const float* w2   = (const float*)d_in[13];
  const float* b2   = (const float*)d_in[14];
  const float* n3g  = (const float*)d_in[15];
  const float* n3b  = (const float*)d_in[16];
  const float* c1w  = (const float*)d_in[17];
  const float* c1b  = (const float*)d_in[18];
  const float* bn1g = (const float*)d_in[19];
  const float* bn1b = (const float*)d_in[20];
  const float* bn1m = (const float*)d_in[21];
  const float* bn1v = (const float*)d_in[22];
  const float* c2w  = (const float*)d_in[23];
  const float* c2b  = (const float*)d_in[24];
  const float* bn2g = (const float*)d_in[25];
  const float* bn2b = (const float*)d_in[26];
  const float* bn2m = (const float*)d_in[27];
  const float* bn2v = (const float*)d_in[28];

  int B = out_size / (224*224*96);
  if (B < 1 || B > 64) B = 4;
  const size_t elems = (size_t)B*224*224*96;

  u16*   wsA = (u16*)d_ws;
  u32*   w8q = (u32*)d_out;
  u32*   w8p = w8q + 13824;
  float* xo  = (float*)d_out;
  u32*   wcv = nullptr;
  if (ws_size >= elems*sizeof(u16) + 82944*sizeof(u32))
    wcv = (u32*)(wsA + elems);

  wprep_k<<<dim3(72), dim3(256), 0, stream>>>(qkvw, projw, w8q, w8p);
  if (wcv) wprep_cv<<<dim3(324), dim3(256), 0, stream>>>(c1w, c2w, wcv);
  attn_k<<<dim3(B*1024), dim3(256), 0, stream>>>(x, ndwi, n1g, n1b, w8q, qkvb, w8p, projb, rpbt, wsA);
  mlp_k<<<dim3(B*784), dim3(256), 0, stream>>>(wsA, w1, b1, w2, b2, n2g, n2b, xo);
  conv1_k<<<dim3(14,28,B), dim3(256), 0, stream>>>(xo, wcv, c1w, c1b, bn1g, bn1b, bn1m, bn1v, n3g, n3b, wsA);
  conv2_k<<<dim3(14,28,B), dim3(256), 0, stream>>>(wsA, wcv ? wcv + 41472 : nullptr, c2w, c2b, bn2g, bn2b, bn2m, bn2v, xo, xo);
}

// Round 12
// 1474.697 us; speedup vs baseline: 1.0787x; 1.0787x over previous
//
#include <hip/hip_runtime.h>
#include <hip/hip_bf16.h>

typedef unsigned int u32;
typedef unsigned short u16;

#define DF __device__ __forceinline__

DF float bf2f(u16 v){ u32 t = ((u32)v)<<16; return __builtin_bit_cast(float, t); }
DF u16 f2bf(float f){
  u32 t = __builtin_bit_cast(u32, f);
  t += 0x7fffu + ((t>>16)&1u);
  return (u16)(t>>16);
}
DF float lo16(u32 p){ return __builtin_bit_cast(float, p<<16); }
DF float hi16(u32 p){ return __builtin_bit_cast(float, p & 0xffff0000u); }
DF u32 pack2(float a, float b){ return (u32)f2bf(a) | (((u32)f2bf(b))<<16); }
DF float gelu(float x){ return 0.5f*x*(1.0f+erff(x*0.70710678118654752f)); }

// dot2: acc += a.lo*b.lo + a.hi*b.hi (bf16 pairs).
// Builtin path (VERIFIED live on this toolchain: R11's asm version dropped
// attn VGPR 116->68 + spilled s[49]; builtin version regalloc is better).
#if defined(__has_builtin)
#if __has_builtin(__builtin_amdgcn_fdot2_f32_bf16)
#define HAVE_DOT2 1
#endif
#endif
#ifdef HAVE_DOT2
DF float dot2bf(u32 a, u32 b, float c){
  typedef __bf16 b2 __attribute__((ext_vector_type(2)));
  return __builtin_amdgcn_fdot2_f32_bf16(__builtin_bit_cast(b2,a), __builtin_bit_cast(b2,b), c, false);
}
#else
DF float dot2bf(u32 a, u32 b, float c){
  float d;
  asm("v_dot2_f32_bf16 %0, %1, %2, %3" : "=v"(d) : "v"(a), "v"(b), "v"(c));
  return d;
}
#endif
DF u32 c4(const uint4 v, int j){ return j==0?v.x : j==1?v.y : j==2?v.z : v.w; }

// ---------------------------------------------------------------------------
// K0: pack qkv/proj weights for dot2 (front of d_out, consumed by attn).
// ---------------------------------------------------------------------------
__global__ void wprep_k(const float* __restrict__ qkvw, const float* __restrict__ projw,
                        u32* __restrict__ w8q, u32* __restrict__ w8p)
{
  int e = blockIdx.x*256 + threadIdx.x;
  if (e < 13824){
    int og = e/384, r = e - og*384, cp = r>>3, k = r&7;
    int o = og*8 + k;
    w8q[e] = pack2(qkvw[o*96 + 2*cp], qkvw[o*96 + 2*cp + 1]);
  } else if (e < 18432){
    int r2 = e - 13824;
    int og = r2/384, r = r2 - og*384, cp = r>>3, k = r&7;
    int o = og*8 + k;
    w8p[r2] = pack2(projw[o*96 + 2*cp], projw[o*96 + 2*cp + 1]);
  }
}

// ---------------------------------------------------------------------------
// K0b: pack conv weights for dot2 into ws tail: [conv][tap][c2(48)][o(96)].
// ---------------------------------------------------------------------------
__global__ void wprep_cv(const float* __restrict__ c1w, const float* __restrict__ c2w,
                         u32* __restrict__ wcv)
{
  int e = blockIdx.x*256 + threadIdx.x;
  if (e >= 82944) return;
  int conv = e / 41472, r = e - conv*41472;
  int tap = r / 4608, r2 = r - tap*4608;
  int c2 = r2 / 96, o = r2 - c2*96;
  const float* s = conv ? c2w : c1w;
  wcv[e] = pack2(s[(o*96 + 2*c2)*9 + tap], s[(o*96 + 2*c2 + 1)*9 + tap]);
}

// ---------------------------------------------------------------------------
// K1: fused windowed attention (3 blocks/CU, 43KB LDS).
// ---------------------------------------------------------------------------
__global__ __launch_bounds__(256,3) void attn_k(
    const float* __restrict__ x, const float* __restrict__ ndwi,
    const float* __restrict__ n1g, const float* __restrict__ n1b,
    const u32* __restrict__ w8q, const float* __restrict__ qb,
    const u32* __restrict__ w8p, const float* __restrict__ pb,
    const float* __restrict__ rpbt, u16* __restrict__ x1o)
{
  __shared__ u32 xp[49*49];
  __shared__ u32 qp[49*49];
  __shared__ u32 kp[49*49];
  __shared__ u16 vpT[96*50];
  __shared__ float rpb[8*169];
  __shared__ float mw[49];
  const int tid = threadIdx.x;
  const int blk = blockIdx.x;
  const int b = blk >> 10, wy = (blk>>5)&31, wx = blk&31;
  const int wv_ = __builtin_amdgcn_readfirstlane(tid >> 6);
  const int ln  = tid & 63;
  const int lnc = ln < 49 ? ln : 48;

  for (int i = tid; i < 1352; i += 256){
    int h = i/169, idx = i - h*169;
    rpb[i] = rpbt[idx*8 + h];
  }
  for (int i = tid; i < 96; i += 256) vpT[i*50 + 49] = 0;

  // LN1 straight from global: 4 lanes per token
  if (tid < 196){
    const int t = tid >> 2, p = tid & 3;
    const int ty = t/7, tx = t - (t/7)*7;
    int sy = wy*7 + ty - 3; if (sy < 0) sy += 224;
    int sx = wx*7 + tx - 3; if (sx < 0) sx += 224;
    const size_t rowb = ((size_t)((b*224 + sy)*224 + sx))*96;
    const float* xr = x + rowb + p*24;
    float c[24];
    #pragma unroll
    for (int q = 0; q < 6; q++){
      float4 v = ((const float4*)xr)[q];
      c[q*4+0]=v.x; c[q*4+1]=v.y; c[q*4+2]=v.z; c[q*4+3]=v.w;
    }
    if (p == 0) mw[t] = ndwi[(size_t)b*50176 + sy*224 + sx];
    float s = 0.f, s2 = 0.f;
    #pragma unroll
    for (int j = 0; j < 24; j++){ s += c[j]; s2 += c[j]*c[j]; }
    s  += __shfl_xor(s, 1);  s  += __shfl_xor(s, 2);
    s2 += __shfl_xor(s2, 1); s2 += __shfl_xor(s2, 2);
    float m = s*(1.f/96.f);
    float rs = rsqrtf(s2*(1.f/96.f) - m*m + 1e-5f);
    #pragma unroll
    for (int jj = 0; jj < 12; jj++){
      float a = (c[2*jj]  -m)*rs*n1g[p*24+2*jj]   + n1b[p*24+2*jj];
      float d = (c[2*jj+1]-m)*rs*n1g[p*24+2*jj+1] + n1b[p*24+2*jj+1];
      xp[t*49 + p*12 + jj] = pack2(a, d);
    }
  }
  __syncthreads();

  // QKV: wave handles 9 output-groups of 8; lane = token
  for (int ogi = 0; ogi < 9; ogi++){
    const int og = wv_*9 + ogi;
    const int o0 = og*8;
    const u32* wrow = w8q + og*384;
    float acc[8];
    #pragma unroll
    for (int k = 0; k < 8; k++) acc[k] = qb[o0+k];
    #pragma unroll 4
    for (int cp = 0; cp < 48; cp++){
      u32 xv = xp[lnc*49 + cp];
      uint4 wa = *(const uint4*)(wrow + cp*8);
      uint4 wb = *(const uint4*)(wrow + cp*8 + 4);
      acc[0] = dot2bf(xv, wa.x, acc[0]); acc[1] = dot2bf(xv, wa.y, acc[1]);
      acc[2] = dot2bf(xv, wa.z, acc[2]); acc[3] = dot2bf(xv, wa.w, acc[3]);
      acc[4] = dot2bf(xv, wb.x, acc[4]); acc[5] = dot2bf(xv, wb.y, acc[5]);
      acc[6] = dot2bf(xv, wb.z, acc[6]); acc[7] = dot2bf(xv, wb.w, acc[7]);
    }
    if (ln < 49){
      if (og < 12){
        const float S = 0.28867513459481287f;
        #pragma unroll
        for (int m = 0; m < 4; m++) qp[ln*49 + og*4 + m] = pack2(acc[2*m]*S, acc[2*m+1]*S);
      } else if (og < 24){
        #pragma unroll
        for (int m = 0; m < 4; m++) kp[ln*49 + (og-12)*4 + m] = pack2(acc[2*m], acc[2*m+1]);
      } else {
        const int o0v = (og-24)*8;
        #pragma unroll
        for (int k = 0; k < 8; k++) vpT[(o0v+k)*50 + ln] = f2bf(acc[k]);
      }
    }
  }
  __syncthreads();

  // attention: task = (head, query row)
  for (int task = tid; task < 392; task += 256){
    int h = task/49, i = task - (task/49)*49;
    int iy = i/7, ix = i - (i/7)*7;
    u32 qv[6];
    #pragma unroll
    for (int e = 0; e < 6; e++) qv[e] = qp[i*49 + h*6 + e];
    const float* rb = &rpb[h*169 + (iy+6)*13 + (ix+6)];
    float s[49]; float mx = -1e30f;
    float mi = mw[i];
    int j = 0;
    #pragma unroll
    for (int jy = 0; jy < 7; jy++)
    #pragma unroll
    for (int jx = 0; jx < 7; jx++, j++){
      const u32* kr = &kp[j*49 + h*6];
      float a = rb[-(jy*13+jx)];
      a = dot2bf(qv[0], kr[0], a); a = dot2bf(qv[1], kr[1], a);
      a = dot2bf(qv[2], kr[2], a); a = dot2bf(qv[3], kr[3], a);
      a = dot2bf(qv[4], kr[4], a); a = dot2bf(qv[5], kr[5], a);
      a = (mi != mw[j]) ? a - 100.f : a;
      s[j] = a; mx = fmaxf(mx, a);
    }
    float l = 0.f;
    #pragma unroll
    for (int jj = 0; jj < 49; jj++){ float p = __expf(s[jj]-mx); s[jj] = p; l += p; }
    float rl = 1.f/l;
    u32 pp[25];
    #pragma unroll
    for (int e = 0; e < 24; e++)
      pp[e] = (__builtin_bit_cast(u32, s[2*e]) >> 16)
            | (__builtin_bit_cast(u32, s[2*e+1]) & 0xffff0000u);
    pp[24] = __builtin_bit_cast(u32, s[48]) >> 16;
    float o[12];
    #pragma unroll
    for (int d = 0; d < 12; d++){
      const u32* vr = (const u32*)(vpT + (h*12+d)*50);
      float od = 0.f;
      #pragma unroll
      for (int e = 0; e < 25; e++) od = dot2bf(pp[e], vr[e], od);
      o[d] = od*rl;
    }
    #pragma unroll
    for (int m = 0; m < 6; m++) xp[i*49 + h*6 + m] = pack2(o[2*m], o[2*m+1]);
  }
  __syncthreads();

  // proj -> bf16 pairs into qp (dead after QK^T)
  for (int ogi = 0; ogi < 3; ogi++){
    const int og = wv_*3 + ogi;
    const int o0 = og*8;
    const u32* wrow = w8p + og*384;
    float acc[8];
    #pragma unroll
    for (int k = 0; k < 8; k++) acc[k] = pb[o0+k];
    #pragma unroll 4
    for (int cp = 0; cp < 48; cp++){
      u32 xv = xp[lnc*49 + cp];
      uint4 wa = *(const uint4*)(wrow + cp*8);
      uint4 wb = *(const uint4*)(wrow + cp*8 + 4);
      acc[0] = dot2bf(xv, wa.x, acc[0]); acc[1] = dot2bf(xv, wa.y, acc[1]);
      acc[2] = dot2bf(xv, wa.z, acc[2]); acc[3] = dot2bf(xv, wa.w, acc[3]);
      acc[4] = dot2bf(xv, wb.x, acc[4]); acc[5] = dot2bf(xv, wb.y, acc[5]);
      acc[6] = dot2bf(xv, wb.z, acc[6]); acc[7] = dot2bf(xv, wb.w, acc[7]);
    }
    if (ln < 49){
      #pragma unroll
      for (int m = 0; m < 4; m++) qp[ln*49 + og*4 + m] = pack2(acc[2*m], acc[2*m+1]);
    }
  }
  __syncthreads();

  // write: reverse roll (-4) + residual
  for (int e = tid; e < 588; e += 256){
    int t = e/12, g = e - (e/12)*12;
    int ty = t/7, tx = t - (t/7)*7;
    int dy = wy*7 + ty - 4; if (dy < 0) dy += 224;
    int dx = wx*7 + tx - 4; if (dx < 0) dx += 224;
    size_t base = ((size_t)((b*224+dy)*224+dx))*96 + g*8;
    float4 r0 = *(const float4*)(x + base);
    float4 r1 = *(const float4*)(x + base + 4);
    const u32* pr = &qp[t*49 + g*4];
    uint4 ov;
    ov.x = pack2(lo16(pr[0])+r0.x, hi16(pr[0])+r0.y);
    ov.y = pack2(lo16(pr[1])+r0.z, hi16(pr[1])+r0.w);
    ov.z = pack2(lo16(pr[2])+r1.x, hi16(pr[2])+r1.y);
    ov.w = pack2(lo16(pr[3])+r1.z, hi16(pr[3])+r1.w);
    *(uint4*)(x1o + base) = ov;
  }
}

// ---------------------------------------------------------------------------
// K2: fused LN2 + MLP + residual, b128-transposed edition (kept from R11).
// ---------------------------------------------------------------------------
__global__ __launch_bounds__(256,2) void mlp_k(
    const u16* __restrict__ x1, const float* __restrict__ w1, const float* __restrict__ b1,
    const float* __restrict__ w2, const float* __restrict__ b2,
    const float* __restrict__ g2, const float* __restrict__ bb2,
    float* __restrict__ x2o)
{
  __shared__ __align__(16) u32 xtT[48*64];   // [cp][tok]
  __shared__ __align__(16) u32 hlT[48*64];   // [hp][tok]
  __shared__ __align__(16) u32 w1l[96*52];   // [hh][cp], row stride 52
  __shared__ __align__(16) u32 w2l[96*52];   // [oc][hp], row stride 52
  __shared__ float b1s[384];
  const int tid = threadIdx.x;
  const size_t t0 = (size_t)blockIdx.x * 64;

  for (int i = tid; i < 384; i += 256) b1s[i] = b1[i];

  // LN2: 4 lanes per token -> xtT transposed
  {
    const int t = tid >> 2, p = tid & 3;
    const u16* xr = x1 + (t0 + t)*96 + p*24;
    float c[24];
    #pragma unroll
    for (int q = 0; q < 3; q++){
      uint4 v = ((const uint4*)xr)[q];
      c[q*8+0]=lo16(v.x); c[q*8+1]=hi16(v.x);
      c[q*8+2]=lo16(v.y); c[q*8+3]=hi16(v.y);
      c[q*8+4]=lo16(v.z); c[q*8+5]=hi16(v.z);
      c[q*8+6]=lo16(v.w); c[q*8+7]=hi16(v.w);
    }
    float s = 0.f, s2 = 0.f;
    #pragma unroll
    for (int j = 0; j < 24; j++){ s += c[j]; s2 += c[j]*c[j]; }
    s  += __shfl_xor(s, 1);  s  += __shfl_xor(s, 2);
    s2 += __shfl_xor(s2, 1); s2 += __shfl_xor(s2, 2);
    float m = s*(1.f/96.f);
    float rs = rsqrtf(s2*(1.f/96.f) - m*m + 1e-5f);
    #pragma unroll
    for (int jj = 0; jj < 12; jj++){
      float a = (c[2*jj]  -m)*rs*g2[p*24+2*jj]   + bb2[p*24+2*jj];
      float d = (c[2*jj+1]-m)*rs*g2[p*24+2*jj+1] + bb2[p*24+2*jj+1];
      xtT[(p*12+jj)*64 + t] = pack2(a, d);
    }
  }

  const int ttg = tid & 15;
  const int hg  = tid >> 4;
  float oacc[4][6];
  #pragma unroll
  for (int i = 0; i < 4; i++)
    #pragma unroll
    for (int k = 0; k < 6; k++) oacc[i][k] = 0.f;

  for (int q = 0; q < 4; q++){
    const int h0 = q*96;
    __syncthreads();
    for (int e = tid; e < 4608; e += 256){
      int r = e/48, cpp = e - (e/48)*48;
      float2 a1 = *(const float2*)(w1 + (size_t)(h0+r)*96 + 2*cpp);
      w1l[r*52+cpp] = pack2(a1.x, a1.y);
      float2 a2 = *(const float2*)(w2 + (size_t)r*384 + h0 + 2*cpp);
      w2l[r*52+cpp] = pack2(a2.x, a2.y);
    }
    __syncthreads();
    float a[4][6];
    #pragma unroll
    for (int i = 0; i < 4; i++)
      #pragma unroll
      for (int k = 0; k < 6; k++) a[i][k] = b1s[h0 + hg*6 + k];
    for (int cb = 0; cb < 12; cb++){
      uint4 xv[4], wv[6];
      #pragma unroll
      for (int j = 0; j < 4; j++) xv[j] = *(const uint4*)&xtT[(cb*4+j)*64 + ttg*4];
      #pragma unroll
      for (int k = 0; k < 6; k++) wv[k] = *(const uint4*)&w1l[(hg*6+k)*52 + cb*4];
      #pragma unroll
      for (int j = 0; j < 4; j++){
        const u32 v0 = xv[j].x, v1 = xv[j].y, v2 = xv[j].z, v3 = xv[j].w;
        #pragma unroll
        for (int k = 0; k < 6; k++){
          const u32 w = c4(wv[k], j);
          a[0][k] = dot2bf(v0, w, a[0][k]);
          a[1][k] = dot2bf(v1, w, a[1][k]);
          a[2][k] = dot2bf(v2, w, a[2][k]);
          a[3][k] = dot2bf(v3, w, a[3][k]);
        }
      }
    }
    #pragma unroll
    for (int i = 0; i < 4; i++)
      #pragma unroll
      for (int p3 = 0; p3 < 3; p3++)
        hlT[(hg*3+p3)*64 + (ttg*4+i)] = pack2(gelu(a[i][2*p3]), gelu(a[i][2*p3+1]));
    __syncthreads();
    for (int hb = 0; hb < 12; hb++){
      uint4 hv[4], wv[6];
      #pragma unroll
      for (int j = 0; j < 4; j++) hv[j] = *(const uint4*)&hlT[(hb*4+j)*64 + ttg*4];
      #pragma unroll
      for (int k = 0; k < 6; k++) wv[k] = *(const uint4*)&w2l[(hg*6+k)*52 + hb*4];
      #pragma unroll
      for (int j = 0; j < 4; j++){
        const u32 v0 = hv[j].x, v1 = hv[j].y, v2 = hv[j].z, v3 = hv[j].w;
        #pragma unroll
        for (int k = 0; k < 6; k++){
          const u32 w = c4(wv[k], j);
          oacc[0][k] = dot2bf(v0, w, oacc[0][k]);
          oacc[1][k] = dot2bf(v1, w, oacc[1][k]);
          oacc[2][k] = dot2bf(v2, w, oacc[2][k]);
          oacc[3][k] = dot2bf(v3, w, oacc[3][k]);
        }
      }
    }
  }

  const int oc0 = hg*6;
  float b2v[6];
  #pragma unroll
  for (int k = 0; k < 6; k++) b2v[k] = b2[oc0+k];
  #pragma unroll
  for (int i = 0; i < 4; i++){
    size_t tok = t0 + ttg*4 + i;
    const u32* rr = (const u32*)(x1 + tok*96 + oc0);
    float* orow = x2o + tok*96 + oc0;
    #pragma unroll
    for (int p3 = 0; p3 < 3; p3++){
      u32 rv = rr[p3];
      float2 st;
      st.x = lo16(rv) + oacc[i][2*p3]   + b2v[2*p3];
      st.y = hi16(rv) + oacc[i][2*p3+1] + b2v[2*p3+1];
      *(float2*)(orow + 2*p3) = st;
    }
  }
}

// ---------------------------------------------------------------------------
// K3a: per-pixel LN3 + 3x3 conv (dil 1) + bias + BN + GELU.
// ---------------------------------------------------------------------------
__global__ __launch_bounds__(256,2) void conv1_k(
    const float* __restrict__ src, const u32* __restrict__ wpk,
    const float* __restrict__ wOIHW,
    const float* __restrict__ cb, const float* __restrict__ bng, const float* __restrict__ bnb,
    const float* __restrict__ bnm, const float* __restrict__ bnv,
    const float* __restrict__ g3, const float* __restrict__ b3,
    u16* __restrict__ dst)
{
  constexpr int DIL = 1, SY = 10, SX = 18;
  __shared__ u32 intile[SY*SX*49];
  __shared__ __align__(16) u32 wsl[4608];
  const int tid = threadIdx.x;
  const int bx = blockIdx.x*16, by = blockIdx.y*8, b = blockIdx.z;
  const int gy0 = by - DIL, gx0 = bx - DIL;
  for (int e = tid; e < SY*SX*48; e += 256){
    int p = e/48, c2 = e - (e/48)*48;
    int y = p/SX, xx = p - (p/SX)*SX;
    int gy = gy0+y, gx = gx0+xx;
    u32 v = 0;
    if (gy >= 0 && gy < 224 && gx >= 0 && gx < 224){
      float2 rd = *(const float2*)(src + ((size_t)((b*224+gy)*224+gx))*96 + c2*2);
      v = pack2(rd.x, rd.y);
    }
    intile[p*49 + c2] = v;
  }
  __syncthreads();
  for (int p = tid; p < SY*SX; p += 256){
    int y = p/SX, xx = p - (p/SX)*SX;
    int gy = gy0+y, gx = gx0+xx;
    if (gy >= 0 && gy < 224 && gx >= 0 && gx < 224){
      u32* row = &intile[p*49];
      float m = 0.f;
      #pragma unroll
      for (int c2 = 0; c2 < 48; c2++){ u32 v = row[c2]; m += lo16(v)+hi16(v); }
      m *= (1.f/96.f);
      float var = 0.f;
      #pragma unroll
      for (int c2 = 0; c2 < 48; c2++){
        u32 v = row[c2];
        float d0 = lo16(v)-m, d1 = hi16(v)-m;
        var += d0*d0 + d1*d1;
      }
      float rs = rsqrtf(var*(1.f/96.f)+1e-5f);
      #pragma unroll
      for (int c2 = 0; c2 < 48; c2++){
        u32 v = row[c2];
        float2 gg = *(const float2*)(g3 + 2*c2);
        float2 bb = *(const float2*)(b3 + 2*c2);
        row[c2] = pack2((lo16(v)-m)*rs*gg.x+bb.x,
                        (hi16(v)-m)*rs*gg.y+bb.y);
      }
    }
  }
  const int pxg = tid & 31, og = tid >> 5;
  const int px8 = pxg & 15, py8 = pxg >> 4;
  const int o0 = og*12;
  float acc[4][12];
  #pragma unroll
  for (int a = 0; a < 4; a++)
    #pragma unroll
    for (int j = 0; j < 12; j++) acc[a][j] = 0.f;

  for (int tap = 0; tap < 9; tap++){
    const int ky = tap/3, kx = tap - (tap/3)*3;
    __syncthreads();
    if (wpk){
      const u32* wsrc = wpk + tap*4608;
      for (int e = tid; e < 4608; e += 256) wsl[e] = wsrc[e];
    } else {
      for (int e = tid; e < 4608; e += 256){
        int c2 = e/96, o = e - (e/96)*96;
        wsl[e] = pack2(wOIHW[(o*96 + 2*c2)*9 + tap], wOIHW[(o*96 + 2*c2 + 1)*9 + tap]);
      }
    }
    __syncthreads();
    for (int c2 = 0; c2 < 48; c2++){
      u32 iv[4];
      #pragma unroll
      for (int a = 0; a < 4; a++)
        iv[a] = intile[((py8+2*a+ky*DIL)*SX + (px8+kx*DIL))*49 + c2];
      const u32* wr = &wsl[c2*96 + o0];
      uint4 wA = *(const uint4*)(wr);
      uint4 wB = *(const uint4*)(wr+4);
      uint4 wC = *(const uint4*)(wr+8);
      #pragma unroll
      for (int a = 0; a < 4; a++){
        u32 v = iv[a];
        acc[a][0]  = dot2bf(v, wA.x, acc[a][0]);
        acc[a][1]  = dot2bf(v, wA.y, acc[a][1]);
        acc[a][2]  = dot2bf(v, wA.z, acc[a][2]);
        acc[a][3]  = dot2bf(v, wA.w, acc[a][3]);
        acc[a][4]  = dot2bf(v, wB.x, acc[a][4]);
        acc[a][5]  = dot2bf(v, wB.y, acc[a][5]);
        acc[a][6]  = dot2bf(v, wB.z, acc[a][6]);
        acc[a][7]  = dot2bf(v, wB.w, acc[a][7]);
        acc[a][8]  = dot2bf(v, wC.x, acc[a][8]);
        acc[a][9]  = dot2bf(v, wC.y, acc[a][9]);
        acc[a][10] = dot2bf(v, wC.z, acc[a][10]);
        acc[a][11] = dot2bf(v, wC.w, acc[a][11]);
      }
    }
  }
  float sc[12], mm[12], bb[12], cbv[12];
  #pragma unroll
  for (int j = 0; j < 12; j++){
    sc[j] = bng[o0+j]*rsqrtf(bnv[o0+j]+1e-5f);
    mm[j] = bnm[o0+j]; bb[j] = bnb[o0+j]; cbv[j] = cb[o0+j];
  }
  #pragma unroll
  for (int a = 0; a < 4; a++){
    int gy = by + py8 + 2*a, gx = bx + px8;
    size_t base = ((size_t)((b*224+gy)*224+gx))*96 + o0;
    #pragma unroll
    for (int d = 0; d < 6; d++){
      float t0 = (acc[a][2*d]   + cbv[2*d]   - mm[2*d])  *sc[2*d]   + bb[2*d];
      float t1 = (acc[a][2*d+1] + cbv[2*d+1] - mm[2*d+1])*sc[2*d+1] + bb[2*d+1];
      *(u32*)(dst + base + 2*d) = pack2(gelu(t0), gelu(t1));
    }
  }
}

// ---------------------------------------------------------------------------
// K3b: 3x3 conv (dil 2) + bias + BN + GELU + residual(x2).
// ---------------------------------------------------------------------------
__global__ __launch_bounds__(256,2) void conv2_k(
    const u16* __restrict__ src, const u32* __restrict__ wpk,
    const float* __restrict__ wOIHW,
    const float* __restrict__ cb, const float* __restrict__ bng, const float* __restrict__ bnb,
    const float* __restrict__ bnm, const float* __restrict__ bnv,
    const float* resid, float* dst)
{
  constexpr int DIL = 2, SY = 12, SX = 20;
  __shared__ u32 intile[SY*SX*49];
  __shared__ __align__(16) u32 wsl[4608];
  const int tid = threadIdx.x;
  const int bx = blockIdx.x*16, by = blockIdx.y*8, b = blockIdx.z;
  const int gy0 = by - DIL, gx0 = bx - DIL;
  for (int e = tid; e < SY*SX*48; e += 256){
    int p = e/48, c2 = e - (e/48)*48;
    int y = p/SX, xx = p - (p/SX)*SX;
    int gy = gy0+y, gx = gx0+xx;
    u32 v = 0;
    if (gy >= 0 && gy < 224 && gx >= 0 && gx < 224)
      v = *(const u32*)(src + ((size_t)((b*224+gy)*224+gx))*96 + c2*2);
    intile[p*49 + c2] = v;
  }
  const int pxg = tid & 31, og = tid >> 5;
  const int px8 = pxg & 15, py8 = pxg >> 4;
  const int o0 = og*12;
  float acc[4][12];
  #pragma unroll
  for (int a = 0; a < 4; a++)
    #pragma unroll
    for (int j = 0; j < 12; j++) acc[a][j] = 0.f;

  for (int tap = 0; tap < 9; tap++){
    const int ky = tap/3, kx = tap - (tap/3)*3;
    __syncthreads();
    if (wpk){
      const u32* wsrc = wpk + tap*4608;
      for (int e = tid; e < 4608; e += 256) wsl[e] = wsrc[e];
    } else {
      for (int e = tid; e < 4608; e += 256){
        int c2 = e/96, o = e - (e/96)*96;
        wsl[e] = pack2(wOIHW[(o*96 + 2*c2)*9 + tap], wOIHW[(o*96 + 2*c2 + 1)*9 + tap]);
      }
    }
    __syncthreads();
    for (int c2 = 0; c2 < 48; c2++){
      u32 iv[4];
      #pragma unroll
      for (int a = 0; a < 4; a++)
        iv[a] = intile[((py8+2*a+ky*DIL)*SX + (px8+kx*DIL))*49 + c2];
      const u32* wr = &wsl[c2*96 + o0];
      uint4 wA = *(const uint4*)(wr);
      uint4 wB = *(const uint4*)(wr+4);
      uint4 wC = *(const uint4*)(wr+8);
      #pragma unroll
      for (int a = 0; a < 4; a++){
        u32 v = iv[a];
        acc[a][0]  = dot2bf(v, wA.x, acc[a][0]);
        acc[a][1]  = dot2bf(v, wA.y, acc[a][1]);
        acc[a][2]  = dot2bf(v, wA.z, acc[a][2]);
        acc[a][3]  = dot2bf(v, wA.w, acc[a][3]);
        acc[a][4]  = dot2bf(v, wB.x, acc[a][4]);
        acc[a][5]  = dot2bf(v, wB.y, acc[a][5]);
        acc[a][6]  = dot2bf(v, wB.z, acc[a][6]);
        acc[a][7]  = dot2bf(v, wB.w, acc[a][7]);
        acc[a][8]  = dot2bf(v, wC.x, acc[a][8]);
        acc[a][9]  = dot2bf(v, wC.y, acc[a][9]);
        acc[a][10] = dot2bf(v, wC.z, acc[a][10]);
        acc[a][11] = dot2bf(v, wC.w, acc[a][11]);
      }
    }
  }
  float sc[12], mm[12], bb[12], cbv[12];
  #pragma unroll
  for (int j = 0; j < 12; j++){
    sc[j] = bng[o0+j]*rsqrtf(bnv[o0+j]+1e-5f);
    mm[j] = bnm[o0+j]; bb[j] = bnb[o0+j]; cbv[j] = cb[o0+j];
  }
  #pragma unroll
  for (int a = 0; a < 4; a++){
    int gy = by + py8 + 2*a, gx = bx + px8;
    size_t base = ((size_t)((b*224+gy)*224+gx))*96 + o0;
    float4 r0 = *(const float4*)(resid + base);
    float4 r1 = *(const float4*)(resid + base + 4);
    float4 r2 = *(const float4*)(resid + base + 8);
    float ov[12];
    #pragma unroll
    for (int j = 0; j < 12; j++){
      float t = (acc[a][j] + cbv[j] - mm[j])*sc[j] + bb[j];
      ov[j] = gelu(t);
    }
    float4 s0, s1, s2;
    s0.x = ov[0]+r0.x;  s0.y = ov[1]+r0.y;  s0.z = ov[2]+r0.z;  s0.w = ov[3]+r0.w;
    s1.x = ov[4]+r1.x;  s1.y = ov[5]+r1.y;  s1.z = ov[6]+r1.z;  s1.w = ov[7]+r1.w;
    s2.x = ov[8]+r2.x;  s2.y = ov[9]+r2.y;  s2.z = ov[10]+r2.z; s2.w = ov[11]+r2.w;
    *(float4*)(dst + base)     = s0;
    *(float4*)(dst + base + 4) = s1;
    *(float4*)(dst + base + 8) = s2;
  }
}

// ---------------------------------------------------------------------------
extern "C" void kernel_launch(void* const* d_in, const int* in_sizes, int n_in,
                              void* d_out, int out_size, void* d_ws, size_t ws_size,
                              hipStream_t stream)
{
  const float* x    = (const float*)d_in[0];
  const float* ndwi = (const float*)d_in[1];
  const float* n1g  = (const float*)d_in[2];
  const float* n1b  = (const float*)d_in[3];
  const float* qkvw = (const float*)d_in[4];
  const float* qkvb = (const float*)d_in[5];
  const float* projw= (const float*)d_in[6];
  const float* projb= (const float*)d_in[7];
  const float* rpbt = (const float*)d_in[8];
  const float* n2g  = (const float*)d_in[9];
  const float* n2b  = (const float*)d_in[10];
  const float* w1   = (const float*)d_in[11];
  const float* b1   = (const float*)d_in[12];
  const float* w2   = (const float*)d_in[13];
  const float* b2   = (const float*)d_in[14];
  const float* n3g  = (const float*)d_in[15];
  const float* n3b  = (const float*)d_in[16];
  const float* c1w  = (const float*)d_in[17];
  const float* c1b  = (const float*)d_in[18];
  const float* bn1g = (const float*)d_in[19];
  const float* bn1b = (const float*)d_in[20];
  const float* bn1m = (const float*)d_in[21];
  const float* bn1v = (const float*)d_in[22];
  const float* c2w  = (const float*)d_in[23];
  const float* c2b  = (const float*)d_in[24];
  const float* bn2g = (const float*)d_in[25];
  const float* bn2b = (const float*)d_in[26];
  const float* bn2m = (const float*)d_in[27];
  const float* bn2v = (const float*)d_in[28];

  int B = out_size / (224*224*96);
  if (B < 1 || B > 64) B = 4;
  const size_t elems = (size_t)B*224*224*96;

  u16*   wsA = (u16*)d_ws;
  u32*   w8q = (u32*)d_out;
  u32*   w8p = w8q + 13824;
  float* xo  = (float*)d_out;
  u32*   wcv = nullptr;
  if (ws_size >= elems*sizeof(u16) + 82944*sizeof(u32))
    wcv = (u32*)(wsA + elems);

  wprep_k<<<dim3(72), dim3(256), 0, stream>>>(qkvw, projw, w8q, w8p);
  if (wcv) wprep_cv<<<dim3(324), dim3(256), 0, stream>>>(c1w, c2w, wcv);
  attn_k<<<dim3(B*1024), dim3(256), 0, stream>>>(x, ndwi, n1g, n1b, w8q, qkvb, w8p, projb, rpbt, wsA);
  mlp_k<<<dim3(B*784), dim3(256), 0, stream>>>(wsA, w1, b1, w2, b2, n2g, n2b, xo);
  conv1_k<<<dim3(14,28,B), dim3(256), 0, stream>>>(xo, wcv, c1w, c1b, bn1g, bn1b, bn1m, bn1v, n3g, n3b, wsA);
  conv2_k<<<dim3(14,28,B), dim3(256), 0, stream>>>(wsA, wcv ? wcv + 41472 : nullptr, c2w, c2b, bn2g, bn2b, bn2m, bn2v, xo, xo);
}

// Round 13
// 1278.678 us; speedup vs baseline: 1.2441x; 1.1533x over previous
//
#include <hip/hip_runtime.h>
#include <hip/hip_bf16.h>

typedef unsigned int u32;
typedef unsigned short u16;

#define DF __device__ __forceinline__

DF float bf2f(u16 v){ u32 t = ((u32)v)<<16; return __builtin_bit_cast(float, t); }
DF u16 f2bf(float f){
  u32 t = __builtin_bit_cast(u32, f);
  t += 0x7fffu + ((t>>16)&1u);
  return (u16)(t>>16);
}
DF float lo16(u32 p){ return __builtin_bit_cast(float, p<<16); }
DF float hi16(u32 p){ return __builtin_bit_cast(float, p & 0xffff0000u); }
DF u32 pack2(float a, float b){ return (u32)f2bf(a) | (((u32)f2bf(b))<<16); }
DF float gelu(float x){ return 0.5f*x*(1.0f+erff(x*0.70710678118654752f)); }

// dot2 (builtin path verified good; asm path wrecks regalloc — R11).
#if defined(__has_builtin)
#if __has_builtin(__builtin_amdgcn_fdot2_f32_bf16)
#define HAVE_DOT2 1
#endif
#endif
#ifdef HAVE_DOT2
DF float dot2bf(u32 a, u32 b, float c){
  typedef __bf16 b2 __attribute__((ext_vector_type(2)));
  return __builtin_amdgcn_fdot2_f32_bf16(__builtin_bit_cast(b2,a), __builtin_bit_cast(b2,b), c, false);
}
#else
DF float dot2bf(u32 a, u32 b, float c){
  float d;
  asm("v_dot2_f32_bf16 %0, %1, %2, %3" : "=v"(d) : "v"(a), "v"(b), "v"(c));
  return d;
}
#endif

typedef __attribute__((ext_vector_type(8))) __bf16 bf16x8;
typedef __attribute__((ext_vector_type(4))) float f32x4;

// ---------------------------------------------------------------------------
// K0: pack qkv/proj weights for dot2 (front of d_out, consumed by attn).
// ---------------------------------------------------------------------------
__global__ void wprep_k(const float* __restrict__ qkvw, const float* __restrict__ projw,
                        u32* __restrict__ w8q, u32* __restrict__ w8p)
{
  int e = blockIdx.x*256 + threadIdx.x;
  if (e < 13824){
    int og = e/384, r = e - og*384, cp = r>>3, k = r&7;
    int o = og*8 + k;
    w8q[e] = pack2(qkvw[o*96 + 2*cp], qkvw[o*96 + 2*cp + 1]);
  } else if (e < 18432){
    int r2 = e - 13824;
    int og = r2/384, r = r2 - og*384, cp = r>>3, k = r&7;
    int o = og*8 + k;
    w8p[r2] = pack2(projw[o*96 + 2*cp], projw[o*96 + 2*cp + 1]);
  }
}

// ---------------------------------------------------------------------------
// K0b: pack conv weights for dot2 into ws tail: [conv][tap][c2(48)][o(96)].
// ---------------------------------------------------------------------------
__global__ void wprep_cv(const float* __restrict__ c1w, const float* __restrict__ c2w,
                         u32* __restrict__ wcv)
{
  int e = blockIdx.x*256 + threadIdx.x;
  if (e >= 82944) return;
  int conv = e / 41472, r = e - conv*41472;
  int tap = r / 4608, r2 = r - tap*4608;
  int c2 = r2 / 96, o = r2 - c2*96;
  const float* s = conv ? c2w : c1w;
  wcv[e] = pack2(s[(o*96 + 2*c2)*9 + tap], s[(o*96 + 2*c2 + 1)*9 + tap]);
}

// ---------------------------------------------------------------------------
// K1: fused windowed attention (3 blocks/CU, 43KB LDS) — unchanged from R12.
// ---------------------------------------------------------------------------
__global__ __launch_bounds__(256,3) void attn_k(
    const float* __restrict__ x, const float* __restrict__ ndwi,
    const float* __restrict__ n1g, const float* __restrict__ n1b,
    const u32* __restrict__ w8q, const float* __restrict__ qb,
    const u32* __restrict__ w8p, const float* __restrict__ pb,
    const float* __restrict__ rpbt, u16* __restrict__ x1o)
{
  __shared__ u32 xp[49*49];
  __shared__ u32 qp[49*49];
  __shared__ u32 kp[49*49];
  __shared__ u16 vpT[96*50];
  __shared__ float rpb[8*169];
  __shared__ float mw[49];
  const int tid = threadIdx.x;
  const int blk = blockIdx.x;
  const int b = blk >> 10, wy = (blk>>5)&31, wx = blk&31;
  const int wv_ = __builtin_amdgcn_readfirstlane(tid >> 6);
  const int ln  = tid & 63;
  const int lnc = ln < 49 ? ln : 48;

  for (int i = tid; i < 1352; i += 256){
    int h = i/169, idx = i - h*169;
    rpb[i] = rpbt[idx*8 + h];
  }
  for (int i = tid; i < 96; i += 256) vpT[i*50 + 49] = 0;

  if (tid < 196){
    const int t = tid >> 2, p = tid & 3;
    const int ty = t/7, tx = t - (t/7)*7;
    int sy = wy*7 + ty - 3; if (sy < 0) sy += 224;
    int sx = wx*7 + tx - 3; if (sx < 0) sx += 224;
    const size_t rowb = ((size_t)((b*224 + sy)*224 + sx))*96;
    const float* xr = x + rowb + p*24;
    float c[24];
    #pragma unroll
    for (int q = 0; q < 6; q++){
      float4 v = ((const float4*)xr)[q];
      c[q*4+0]=v.x; c[q*4+1]=v.y; c[q*4+2]=v.z; c[q*4+3]=v.w;
    }
    if (p == 0) mw[t] = ndwi[(size_t)b*50176 + sy*224 + sx];
    float s = 0.f, s2 = 0.f;
    #pragma unroll
    for (int j = 0; j < 24; j++){ s += c[j]; s2 += c[j]*c[j]; }
    s  += __shfl_xor(s, 1);  s  += __shfl_xor(s, 2);
    s2 += __shfl_xor(s2, 1); s2 += __shfl_xor(s2, 2);
    float m = s*(1.f/96.f);
    float rs = rsqrtf(s2*(1.f/96.f) - m*m + 1e-5f);
    #pragma unroll
    for (int jj = 0; jj < 12; jj++){
      float a = (c[2*jj]  -m)*rs*n1g[p*24+2*jj]   + n1b[p*24+2*jj];
      float d = (c[2*jj+1]-m)*rs*n1g[p*24+2*jj+1] + n1b[p*24+2*jj+1];
      xp[t*49 + p*12 + jj] = pack2(a, d);
    }
  }
  __syncthreads();

  for (int ogi = 0; ogi < 9; ogi++){
    const int og = wv_*9 + ogi;
    const int o0 = og*8;
    const u32* wrow = w8q + og*384;
    float acc[8];
    #pragma unroll
    for (int k = 0; k < 8; k++) acc[k] = qb[o0+k];
    #pragma unroll 4
    for (int cp = 0; cp < 48; cp++){
      u32 xv = xp[lnc*49 + cp];
      uint4 wa = *(const uint4*)(wrow + cp*8);
      uint4 wb = *(const uint4*)(wrow + cp*8 + 4);
      acc[0] = dot2bf(xv, wa.x, acc[0]); acc[1] = dot2bf(xv, wa.y, acc[1]);
      acc[2] = dot2bf(xv, wa.z, acc[2]); acc[3] = dot2bf(xv, wa.w, acc[3]);
      acc[4] = dot2bf(xv, wb.x, acc[4]); acc[5] = dot2bf(xv, wb.y, acc[5]);
      acc[6] = dot2bf(xv, wb.z, acc[6]); acc[7] = dot2bf(xv, wb.w, acc[7]);
    }
    if (ln < 49){
      if (og < 12){
        const float S = 0.28867513459481287f;
        #pragma unroll
        for (int m = 0; m < 4; m++) qp[ln*49 + og*4 + m] = pack2(acc[2*m]*S, acc[2*m+1]*S);
      } else if (og < 24){
        #pragma unroll
        for (int m = 0; m < 4; m++) kp[ln*49 + (og-12)*4 + m] = pack2(acc[2*m], acc[2*m+1]);
      } else {
        const int o0v = (og-24)*8;
        #pragma unroll
        for (int k = 0; k < 8; k++) vpT[(o0v+k)*50 + ln] = f2bf(acc[k]);
      }
    }
  }
  __syncthreads();

  for (int task = tid; task < 392; task += 256){
    int h = task/49, i = task - (task/49)*49;
    int iy = i/7, ix = i - (i/7)*7;
    u32 qv[6];
    #pragma unroll
    for (int e = 0; e < 6; e++) qv[e] = qp[i*49 + h*6 + e];
    const float* rb = &rpb[h*169 + (iy+6)*13 + (ix+6)];
    float s[49]; float mx = -1e30f;
    float mi = mw[i];
    int j = 0;
    #pragma unroll
    for (int jy = 0; jy < 7; jy++)
    #pragma unroll
    for (int jx = 0; jx < 7; jx++, j++){
      const u32* kr = &kp[j*49 + h*6];
      float a = rb[-(jy*13+jx)];
      a = dot2bf(qv[0], kr[0], a); a = dot2bf(qv[1], kr[1], a);
      a = dot2bf(qv[2], kr[2], a); a = dot2bf(qv[3], kr[3], a);
      a = dot2bf(qv[4], kr[4], a); a = dot2bf(qv[5], kr[5], a);
      a = (mi != mw[j]) ? a - 100.f : a;
      s[j] = a; mx = fmaxf(mx, a);
    }
    float l = 0.f;
    #pragma unroll
    for (int jj = 0; jj < 49; jj++){ float p = __expf(s[jj]-mx); s[jj] = p; l += p; }
    float rl = 1.f/l;
    u32 pp[25];
    #pragma unroll
    for (int e = 0; e < 24; e++)
      pp[e] = (__builtin_bit_cast(u32, s[2*e]) >> 16)
            | (__builtin_bit_cast(u32, s[2*e+1]) & 0xffff0000u);
    pp[24] = __builtin_bit_cast(u32, s[48]) >> 16;
    float o[12];
    #pragma unroll
    for (int d = 0; d < 12; d++){
      const u32* vr = (const u32*)(vpT + (h*12+d)*50);
      float od = 0.f;
      #pragma unroll
      for (int e = 0; e < 25; e++) od = dot2bf(pp[e], vr[e], od);
      o[d] = od*rl;
    }
    #pragma unroll
    for (int m = 0; m < 6; m++) xp[i*49 + h*6 + m] = pack2(o[2*m], o[2*m+1]);
  }
  __syncthreads();

  for (int ogi = 0; ogi < 3; ogi++){
    const int og = wv_*3 + ogi;
    const int o0 = og*8;
    const u32* wrow = w8p + og*384;
    float acc[8];
    #pragma unroll
    for (int k = 0; k < 8; k++) acc[k] = pb[o0+k];
    #pragma unroll 4
    for (int cp = 0; cp < 48; cp++){
      u32 xv = xp[lnc*49 + cp];
      uint4 wa = *(const uint4*)(wrow + cp*8);
      uint4 wb = *(const uint4*)(wrow + cp*8 + 4);
      acc[0] = dot2bf(xv, wa.x, acc[0]); acc[1] = dot2bf(xv, wa.y, acc[1]);
      acc[2] = dot2bf(xv, wa.z, acc[2]); acc[3] = dot2bf(xv, wa.w, acc[3]);
      acc[4] = dot2bf(xv, wb.x, acc[4]); acc[5] = dot2bf(xv, wb.y, acc[5]);
      acc[6] = dot2bf(xv, wb.z, acc[6]); acc[7] = dot2bf(xv, wb.w, acc[7]);
    }
    if (ln < 49){
      #pragma unroll
      for (int m = 0; m < 4; m++) qp[ln*49 + og*4 + m] = pack2(acc[2*m], acc[2*m+1]);
    }
  }
  __syncthreads();

  for (int e = tid; e < 588; e += 256){
    int t = e/12, g = e - (e/12)*12;
    int ty = t/7, tx = t - (t/7)*7;
    int dy = wy*7 + ty - 4; if (dy < 0) dy += 224;
    int dx = wx*7 + tx - 4; if (dx < 0) dx += 224;
    size_t base = ((size_t)((b*224+dy)*224+dx))*96 + g*8;
    float4 r0 = *(const float4*)(x + base);
    float4 r1 = *(const float4*)(x + base + 4);
    const u32* pr = &qp[t*49 + g*4];
    uint4 ov;
    ov.x = pack2(lo16(pr[0])+r0.x, hi16(pr[0])+r0.y);
    ov.y = pack2(lo16(pr[1])+r0.z, hi16(pr[1])+r0.w);
    ov.z = pack2(lo16(pr[2])+r1.x, hi16(pr[2])+r1.y);
    ov.w = pack2(lo16(pr[3])+r1.z, hi16(pr[3])+r1.w);
    *(uint4*)(x1o + base) = ov;
  }
}

// ---------------------------------------------------------------------------
// K2: fused LN2 + MLP + residual — MFMA 16x16x32 bf16 edition.
// 64 tok/block, 4 waves, wave = m-tile. Fragment-major LDS (lane-contiguous
// 16B b128 reads, conflict-free). GEMM1 (K=96) -> gelu -> GEMM2 (K=384,
// accumulated over 4 hidden-quarters in f32x4 regs). LDS 60KB -> 2 blk/CU.
// Fragment maps: A row=lane&15, k=(lane>>4)*8+i ; B col=lane&15 same k;
// D col=lane&15, row=(lane>>4)*4+r  [C/D HW-verified mapping].
// ---------------------------------------------------------------------------
__global__ __launch_bounds__(256,2) void mlp_k(
    const u16* __restrict__ x1, const float* __restrict__ w1, const float* __restrict__ b1,
    const float* __restrict__ w2, const float* __restrict__ b2,
    const float* __restrict__ g2, const float* __restrict__ bb2,
    float* __restrict__ x2o)
{
  __shared__ __align__(16) u16 xA [4*3*64*8];   // 12KB  LN'd x A-frags
  __shared__ __align__(16) u16 hA [4*3*64*8];   // 12KB  gelu(h) A-frags (per quarter)
  __shared__ __align__(16) u16 w1f[6*3*64*8];   // 18KB  w1 quarter B-frags
  __shared__ __align__(16) u16 w2f[6*3*64*8];   // 18KB  w2 quarter B-frags
  const int tid = threadIdx.x;
  const size_t t0 = (size_t)blockIdx.x * 64;
  const int wvM = tid >> 6;      // wave = m-tile (16 tokens)
  const int ln  = tid & 63;
  const int colv = ln & 15, rgrp = ln >> 4;

  // LN2 -> xA fragments (4 lanes per token)
  {
    const int t = tid >> 2, p = tid & 3;
    const u16* xr = x1 + (t0 + t)*96 + p*24;
    float c[24];
    #pragma unroll
    for (int q = 0; q < 3; q++){
      uint4 v = ((const uint4*)xr)[q];
      c[q*8+0]=lo16(v.x); c[q*8+1]=hi16(v.x);
      c[q*8+2]=lo16(v.y); c[q*8+3]=hi16(v.y);
      c[q*8+4]=lo16(v.z); c[q*8+5]=hi16(v.z);
      c[q*8+6]=lo16(v.w); c[q*8+7]=hi16(v.w);
    }
    float s = 0.f, s2 = 0.f;
    #pragma unroll
    for (int j = 0; j < 24; j++){ s += c[j]; s2 += c[j]*c[j]; }
    s  += __shfl_xor(s, 1);  s  += __shfl_xor(s, 2);
    s2 += __shfl_xor(s2, 1); s2 += __shfl_xor(s2, 2);
    float m = s*(1.f/96.f);
    float rs = rsqrtf(s2*(1.f/96.f) - m*m + 1e-5f);
    const int mt = t >> 4, row = t & 15;
    #pragma unroll
    for (int jj = 0; jj < 12; jj++){
      int k = p*24 + 2*jj;
      float a = (c[2*jj]  -m)*rs*g2[k]   + bb2[k];
      float d = (c[2*jj+1]-m)*rs*g2[k+1] + bb2[k+1];
      int ks = k >> 5, g = (k & 31) >> 3, i = k & 7;
      *(u32*)&xA[(((mt*3 + ks)*64 + g*16 + row)<<3) + i] = pack2(a, d);
    }
  }

  f32x4 acc2[6];
  #pragma unroll
  for (int j = 0; j < 6; j++) acc2[j] = (f32x4){0.f,0.f,0.f,0.f};

  for (int q = 0; q < 4; q++){
    __syncthreads();   // previous-quarter readers done before restage
    // stage w1/w2 quarter as B-fragments
    for (int e = tid; e < 4608; e += 256){
      int n = e/48, cp = e - (e/48)*48, k = cp*2;
      int ks = k >> 5, g = (k & 31) >> 3, i = k & 7;
      int fidx = ((((n>>4)*3 + ks)*64 + g*16 + (n&15))<<3) + i;
      {
        const float* s = w1 + (size_t)(q*96 + n)*96 + k;     // [hidden][c]
        *(u32*)&w1f[fidx] = pack2(s[0], s[1]);
      }
      {
        const float* s = w2 + (size_t)n*384 + q*96 + k;      // [oc][hidden]
        *(u32*)&w2f[fidx] = pack2(s[0], s[1]);
      }
    }
    __syncthreads();

    // GEMM1: h_q = gelu(xn @ w1_q^T + b1_q)  -> hA fragments
    bf16x8 af[3];
    #pragma unroll
    for (int ks = 0; ks < 3; ks++)
      af[ks] = *(const bf16x8*)&xA[((wvM*3 + ks)*64 + ln)*8];
    #pragma unroll
    for (int j = 0; j < 6; j++){
      f32x4 c = (f32x4){0.f,0.f,0.f,0.f};
      #pragma unroll
      for (int ks = 0; ks < 3; ks++){
        bf16x8 bfv = *(const bf16x8*)&w1f[((j*3 + ks)*64 + ln)*8];
        c = __builtin_amdgcn_mfma_f32_16x16x32_bf16(af[ks], bfv, c, 0, 0, 0);
      }
      const float bv = b1[q*96 + j*16 + colv];
      const int kq = j*16 + colv;                      // hidden-local = GEMM2 k
      const int ks2 = kq >> 5, gg = (kq & 31) >> 3, ii = kq & 7;
      u16* hdst = &hA[(((wvM*3 + ks2)*64 + gg*16)<<3) + ii];
      #pragma unroll
      for (int r = 0; r < 4; r++){
        int rowh = rgrp*4 + r;                         // token-in-tile
        hdst[rowh*8] = f2bf(gelu(c[r] + bv));
      }
    }
    __syncthreads();

    // GEMM2 partial: acc2 += h_q @ w2_q^T
    bf16x8 hf[3];
    #pragma unroll
    for (int ks = 0; ks < 3; ks++)
      hf[ks] = *(const bf16x8*)&hA[((wvM*3 + ks)*64 + ln)*8];
    #pragma unroll
    for (int j = 0; j < 6; j++){
      #pragma unroll
      for (int ks = 0; ks < 3; ks++){
        bf16x8 bfv = *(const bf16x8*)&w2f[((j*3 + ks)*64 + ln)*8];
        acc2[j] = __builtin_amdgcn_mfma_f32_16x16x32_bf16(hf[ks], bfv, acc2[j], 0, 0, 0);
      }
    }
  }

  // epilogue: x2 = x1 + mlp_out + b2   (f32 to d_out)
  #pragma unroll
  for (int j = 0; j < 6; j++){
    const int oc = j*16 + colv;
    const float bv = b2[oc];
    #pragma unroll
    for (int r = 0; r < 4; r++){
      size_t tok = t0 + wvM*16 + rgrp*4 + r;
      x2o[tok*96 + oc] = acc2[j][r] + bv + bf2f(x1[tok*96 + oc]);
    }
  }
}

// ---------------------------------------------------------------------------
// K3a: per-pixel LN3 + 3x3 conv (dil 1) + bias + BN + GELU — unchanged.
// ---------------------------------------------------------------------------
__global__ __launch_bounds__(256,2) void conv1_k(
    const float* __restrict__ src, const u32* __restrict__ wpk,
    const float* __restrict__ wOIHW,
    const float* __restrict__ cb, const float* __restrict__ bng, const float* __restrict__ bnb,
    const float* __restrict__ bnm, const float* __restrict__ bnv,
    const float* __restrict__ g3, const float* __restrict__ b3,
    u16* __restrict__ dst)
{
  constexpr int DIL = 1, SY = 10, SX = 18;
  __shared__ u32 intile[SY*SX*49];
  __shared__ __align__(16) u32 wsl[4608];
  const int tid = threadIdx.x;
  const int bx = blockIdx.x*16, by = blockIdx.y*8, b = blockIdx.z;
  const int gy0 = by - DIL, gx0 = bx - DIL;
  for (int e = tid; e < SY*SX*48; e += 256){
    int p = e/48, c2 = e - (e/48)*48;
    int y = p/SX, xx = p - (p/SX)*SX;
    int gy = gy0+y, gx = gx0+xx;
    u32 v = 0;
    if (gy >= 0 && gy < 224 && gx >= 0 && gx < 224){
      float2 rd = *(const float2*)(src + ((size_t)((b*224+gy)*224+gx))*96 + c2*2);
      v = pack2(rd.x, rd.y);
    }
    intile[p*49 + c2] = v;
  }
  __syncthreads();
  for (int p = tid; p < SY*SX; p += 256){
    int y = p/SX, xx = p - (p/SX)*SX;
    int gy = gy0+y, gx = gx0+xx;
    if (gy >= 0 && gy < 224 && gx >= 0 && gx < 224){
      u32* row = &intile[p*49];
      float m = 0.f;
      #pragma unroll
      for (int c2 = 0; c2 < 48; c2++){ u32 v = row[c2]; m += lo16(v)+hi16(v); }
      m *= (1.f/96.f);
      float var = 0.f;
      #pragma unroll
      for (int c2 = 0; c2 < 48; c2++){
        u32 v = row[c2];
        float d0 = lo16(v)-m, d1 = hi16(v)-m;
        var += d0*d0 + d1*d1;
      }
      float rs = rsqrtf(var*(1.f/96.f)+1e-5f);
      #pragma unroll
      for (int c2 = 0; c2 < 48; c2++){
        u32 v = row[c2];
        float2 gg = *(const float2*)(g3 + 2*c2);
        float2 bb = *(const float2*)(b3 + 2*c2);
        row[c2] = pack2((lo16(v)-m)*rs*gg.x+bb.x,
                        (hi16(v)-m)*rs*gg.y+bb.y);
      }
    }
  }
  const int pxg = tid & 31, og = tid >> 5;
  const int px8 = pxg & 15, py8 = pxg >> 4;
  const int o0 = og*12;
  float acc[4][12];
  #pragma unroll
  for (int a = 0; a < 4; a++)
    #pragma unroll
    for (int j = 0; j < 12; j++) acc[a][j] = 0.f;

  for (int tap = 0; tap < 9; tap++){
    const int ky = tap/3, kx = tap - (tap/3)*3;
    __syncthreads();
    if (wpk){
      const u32* wsrc = wpk + tap*4608;
      for (int e = tid; e < 4608; e += 256) wsl[e] = wsrc[e];
    } else {
      for (int e = tid; e < 4608; e += 256){
        int c2 = e/96, o = e - (e/96)*96;
        wsl[e] = pack2(wOIHW[(o*96 + 2*c2)*9 + tap], wOIHW[(o*96 + 2*c2 + 1)*9 + tap]);
      }
    }
    __syncthreads();
    for (int c2 = 0; c2 < 48; c2++){
      u32 iv[4];
      #pragma unroll
      for (int a = 0; a < 4; a++)
        iv[a] = intile[((py8+2*a+ky*DIL)*SX + (px8+kx*DIL))*49 + c2];
      const u32* wr = &wsl[c2*96 + o0];
      uint4 wA = *(const uint4*)(wr);
      uint4 wB = *(const uint4*)(wr+4);
      uint4 wC = *(const uint4*)(wr+8);
      #pragma unroll
      for (int a = 0; a < 4; a++){
        u32 v = iv[a];
        acc[a][0]  = dot2bf(v, wA.x, acc[a][0]);
        acc[a][1]  = dot2bf(v, wA.y, acc[a][1]);
        acc[a][2]  = dot2bf(v, wA.z, acc[a][2]);
        acc[a][3]  = dot2bf(v, wA.w, acc[a][3]);
        acc[a][4]  = dot2bf(v, wB.x, acc[a][4]);
        acc[a][5]  = dot2bf(v, wB.y, acc[a][5]);
        acc[a][6]  = dot2bf(v, wB.z, acc[a][6]);
        acc[a][7]  = dot2bf(v, wB.w, acc[a][7]);
        acc[a][8]  = dot2bf(v, wC.x, acc[a][8]);
        acc[a][9]  = dot2bf(v, wC.y, acc[a][9]);
        acc[a][10] = dot2bf(v, wC.z, acc[a][10]);
        acc[a][11] = dot2bf(v, wC.w, acc[a][11]);
      }
    }
  }
  float sc[12], mm[12], bb[12], cbv[12];
  #pragma unroll
  for (int j = 0; j < 12; j++){
    sc[j] = bng[o0+j]*rsqrtf(bnv[o0+j]+1e-5f);
    mm[j] = bnm[o0+j]; bb[j] = bnb[o0+j]; cbv[j] = cb[o0+j];
  }
  #pragma unroll
  for (int a = 0; a < 4; a++){
    int gy = by + py8 + 2*a, gx = bx + px8;
    size_t base = ((size_t)((b*224+gy)*224+gx))*96 + o0;
    #pragma unroll
    for (int d = 0; d < 6; d++){
      float t0 = (acc[a][2*d]   + cbv[2*d]   - mm[2*d])  *sc[2*d]   + bb[2*d];
      float t1 = (acc[a][2*d+1] + cbv[2*d+1] - mm[2*d+1])*sc[2*d+1] + bb[2*d+1];
      *(u32*)(dst + base + 2*d) = pack2(gelu(t0), gelu(t1));
    }
  }
}

// ---------------------------------------------------------------------------
// K3b: 3x3 conv (dil 2) + bias + BN + GELU + residual(x2) — unchanged.
// ---------------------------------------------------------------------------
__global__ __launch_bounds__(256,2) void conv2_k(
    const u16* __restrict__ src, const u32* __restrict__ wpk,
    const float* __restrict__ wOIHW,
    const float* __restrict__ cb, const float* __restrict__ bng, const float* __restrict__ bnb,
    const float* __restrict__ bnm, const float* __restrict__ bnv,
    const float* resid, float* dst)
{
  constexpr int DIL = 2, SY = 12, SX = 20;
  __shared__ u32 intile[SY*SX*49];
  __shared__ __align__(16) u32 wsl[4608];
  const int tid = threadIdx.x;
  const int bx = blockIdx.x*16, by = blockIdx.y*8, b = blockIdx.z;
  const int gy0 = by - DIL, gx0 = bx - DIL;
  for (int e = tid; e < SY*SX*48; e += 256){
    int p = e/48, c2 = e - (e/48)*48;
    int y = p/SX, xx = p - (p/SX)*SX;
    int gy = gy0+y, gx = gx0+xx;
    u32 v = 0;
    if (gy >= 0 && gy < 224 && gx >= 0 && gx < 224)
      v = *(const u32*)(src + ((size_t)((b*224+gy)*224+gx))*96 + c2*2);
    intile[p*49 + c2] = v;
  }
  const int pxg = tid & 31, og = tid >> 5;
  const int px8 = pxg & 15, py8 = pxg >> 4;
  const int o0 = og*12;
  float acc[4][12];
  #pragma unroll
  for (int a = 0; a < 4; a++)
    #pragma unroll
    for (int j = 0; j < 12; j++) acc[a][j] = 0.f;

  for (int tap = 0; tap < 9; tap++){
    const int ky = tap/3, kx = tap - (tap/3)*3;
    __syncthreads();
    if (wpk){
      const u32* wsrc = wpk + tap*4608;
      for (int e = tid; e < 4608; e += 256) wsl[e] = wsrc[e];
    } else {
      for (int e = tid; e < 4608; e += 256){
        int c2 = e/96, o = e - (e/96)*96;
        wsl[e] = pack2(wOIHW[(o*96 + 2*c2)*9 + tap], wOIHW[(o*96 + 2*c2 + 1)*9 + tap]);
      }
    }
    __syncthreads();
    for (int c2 = 0; c2 < 48; c2++){
      u32 iv[4];
      #pragma unroll
      for (int a = 0; a < 4; a++)
        iv[a] = intile[((py8+2*a+ky*DIL)*SX + (px8+kx*DIL))*49 + c2];
      const u32* wr = &wsl[c2*96 + o0];
      uint4 wA = *(const uint4*)(wr);
      uint4 wB = *(const uint4*)(wr+4);
      uint4 wC = *(const uint4*)(wr+8);
      #pragma unroll
      for (int a = 0; a < 4; a++){
        u32 v = iv[a];
        acc[a][0]  = dot2bf(v, wA.x, acc[a][0]);
        acc[a][1]  = dot2bf(v, wA.y, acc[a][1]);
        acc[a][2]  = dot2bf(v, wA.z, acc[a][2]);
        acc[a][3]  = dot2bf(v, wA.w, acc[a][3]);
        acc[a][4]  = dot2bf(v, wB.x, acc[a][4]);
        acc[a][5]  = dot2bf(v, wB.y, acc[a][5]);
        acc[a][6]  = dot2bf(v, wB.z, acc[a][6]);
        acc[a][7]  = dot2bf(v, wB.w, acc[a][7]);
        acc[a][8]  = dot2bf(v, wC.x, acc[a][8]);
        acc[a][9]  = dot2bf(v, wC.y, acc[a][9]);
        acc[a][10] = dot2bf(v, wC.z, acc[a][10]);
        acc[a][11] = dot2bf(v, wC.w, acc[a][11]);
      }
    }
  }
  float sc[12], mm[12], bb[12], cbv[12];
  #pragma unroll
  for (int j = 0; j < 12; j++){
    sc[j] = bng[o0+j]*rsqrtf(bnv[o0+j]+1e-5f);
    mm[j] = bnm[o0+j]; bb[j] = bnb[o0+j]; cbv[j] = cb[o0+j];
  }
  #pragma unroll
  for (int a = 0; a < 4; a++){
    int gy = by + py8 + 2*a, gx = bx + px8;
    size_t base = ((size_t)((b*224+gy)*224+gx))*96 + o0;
    float4 r0 = *(const float4*)(resid + base);
    float4 r1 = *(const float4*)(resid + base + 4);
    float4 r2 = *(const float4*)(resid + base + 8);
    float ov[12];
    #pragma unroll
    for (int j = 0; j < 12; j++){
      float t = (acc[a][j] + cbv[j] - mm[j])*sc[j] + bb[j];
      ov[j] = gelu(t);
    }
    float4 s0, s1, s2;
    s0.x = ov[0]+r0.x;  s0.y = ov[1]+r0.y;  s0.z = ov[2]+r0.z;  s0.w = ov[3]+r0.w;
    s1.x = ov[4]+r1.x;  s1.y = ov[5]+r1.y;  s1.z = ov[6]+r1.z;  s1.w = ov[7]+r1.w;
    s2.x = ov[8]+r2.x;  s2.y = ov[9]+r2.y;  s2.z = ov[10]+r2.z; s2.w = ov[11]+r2.w;
    *(float4*)(dst + base)     = s0;
    *(float4*)(dst + base + 4) = s1;
    *(float4*)(dst + base + 8) = s2;
  }
}

// ---------------------------------------------------------------------------
extern "C" void kernel_launch(void* const* d_in, const int* in_sizes, int n_in,
                              void* d_out, int out_size, void* d_ws, size_t ws_size,
                              hipStream_t stream)
{
  const float* x    = (const float*)d_in[0];
  const float* ndwi = (const float*)d_in[1];
  const float* n1g  = (const float*)d_in[2];
  const float* n1b  = (const float*)d_in[3];
  const float* qkvw = (const float*)d_in[4];
  const float* qkvb = (const float*)d_in[5];
  const float* projw= (const float*)d_in[6];
  const float* projb= (const float*)d_in[7];
  const float* rpbt = (const float*)d_in[8];
  const float* n2g  = (const float*)d_in[9];
  const float* n2b  = (const float*)d_in[10];
  const float* w1   = (const float*)d_in[11];
  const float* b1   = (const float*)d_in[12];
  const float* w2   = (const float*)d_in[13];
  const float* b2   = (const float*)d_in[14];
  const float* n3g  = (const float*)d_in[15];
  const float* n3b  = (const float*)d_in[16];
  const float* c1w  = (const float*)d_in[17];
  const float* c1b  = (const float*)d_in[18];
  const float* bn1g = (const float*)d_in[19];
  const float* bn1b = (const float*)d_in[20];
  const float* bn1m = (const float*)d_in[21];
  const float* bn1v = (const float*)d_in[22];
  const float* c2w  = (const float*)d_in[23];
  const float* c2b  = (const float*)d_in[24];
  const float* bn2g = (const float*)d_in[25];
  const float* bn2b = (const float*)d_in[26];
  const float* bn2m = (const float*)d_in[27];
  const float* bn2v = (const float*)d_in[28];

  int B = out_size / (224*224*96);
  if (B < 1 || B > 64) B = 4;
  const size_t elems = (size_t)B*224*224*96;

  u16*   wsA = (u16*)d_ws;
  u32*   w8q = (u32*)d_out;
  u32*   w8p = w8q + 13824;
  float* xo  = (float*)d_out;
  u32*   wcv = nullptr;
  if (ws_size >= elems*sizeof(u16) + 82944*sizeof(u32))
    wcv = (u32*)(wsA + elems);

  wprep_k<<<dim3(72), dim3(256), 0, stream>>>(qkvw, projw, w8q, w8p);
  if (wcv) wprep_cv<<<dim3(324), dim3(256), 0, stream>>>(c1w, c2w, wcv);
  attn_k<<<dim3(B*1024), dim3(256), 0, stream>>>(x, ndwi, n1g, n1b, w8q, qkvb, w8p, projb, rpbt, wsA);
  mlp_k<<<dim3(B*784), dim3(256), 0, stream>>>(wsA, w1, b1, w2, b2, n2g, n2b, xo);
  conv1_k<<<dim3(14,28,B), dim3(256), 0, stream>>>(xo, wcv, c1w, c1b, bn1g, bn1b, bn1m, bn1v, n3g, n3b, wsA);
  conv2_k<<<dim3(14,28,B), dim3(256), 0, stream>>>(wsA, wcv ? wcv + 41472 : nullptr, c2w, c2b, bn2g, bn2b, bn2m, bn2v, xo, xo);
}

// Round 14
// 808.222 us; speedup vs baseline: 1.9683x; 1.5821x over previous
//
#include <hip/hip_runtime.h>
#include <hip/hip_bf16.h>

typedef unsigned int u32;
typedef unsigned short u16;

#define DF __device__ __forceinline__

DF float bf2f(u16 v){ u32 t = ((u32)v)<<16; return __builtin_bit_cast(float, t); }
DF u16 f2bf(float f){
  u32 t = __builtin_bit_cast(u32, f);
  t += 0x7fffu + ((t>>16)&1u);
  return (u16)(t>>16);
}
DF float lo16(u32 p){ return __builtin_bit_cast(float, p<<16); }
DF float hi16(u32 p){ return __builtin_bit_cast(float, p & 0xffff0000u); }
DF u32 pack2(float a, float b){ return (u32)f2bf(a) | (((u32)f2bf(b))<<16); }
DF float gelu(float x){ return 0.5f*x*(1.0f+erff(x*0.70710678118654752f)); }

// dot2 (builtin path verified good; asm path wrecks regalloc — R11).
#if defined(__has_builtin)
#if __has_builtin(__builtin_amdgcn_fdot2_f32_bf16)
#define HAVE_DOT2 1
#endif
#endif
#ifdef HAVE_DOT2
DF float dot2bf(u32 a, u32 b, float c){
  typedef __bf16 b2 __attribute__((ext_vector_type(2)));
  return __builtin_amdgcn_fdot2_f32_bf16(__builtin_bit_cast(b2,a), __builtin_bit_cast(b2,b), c, false);
}
#else
DF float dot2bf(u32 a, u32 b, float c){
  float d;
  asm("v_dot2_f32_bf16 %0, %1, %2, %3" : "=v"(d) : "v"(a), "v"(b), "v"(c));
  return d;
}
#endif

typedef __attribute__((ext_vector_type(8))) __bf16 bf16x8;
typedef __attribute__((ext_vector_type(4))) float f32x4;

// ---------------------------------------------------------------------------
// K0: pack qkv/proj weights for dot2 (front of d_out, consumed by attn).
// ---------------------------------------------------------------------------
__global__ void wprep_k(const float* __restrict__ qkvw, const float* __restrict__ projw,
                        u32* __restrict__ w8q, u32* __restrict__ w8p)
{
  int e = blockIdx.x*256 + threadIdx.x;
  if (e < 13824){
    int og = e/384, r = e - og*384, cp = r>>3, k = r&7;
    int o = og*8 + k;
    w8q[e] = pack2(qkvw[o*96 + 2*cp], qkvw[o*96 + 2*cp + 1]);
  } else if (e < 18432){
    int r2 = e - 13824;
    int og = r2/384, r = r2 - og*384, cp = r>>3, k = r&7;
    int o = og*8 + k;
    w8p[r2] = pack2(projw[o*96 + 2*cp], projw[o*96 + 2*cp + 1]);
  }
}

// ---------------------------------------------------------------------------
// K0b: pack conv weights as MFMA B-FRAGMENTS into ws tail:
// [conv][tap(9)][j(6)][ks(3)][lane(64)][4 u32]; n=j*16+(lane&15),
// k=ks*32+(lane>>4)*8+2q. Same (lane,i)->k map as mlp (HW-verified).
// ---------------------------------------------------------------------------
__global__ void wprep_cv(const float* __restrict__ c1w, const float* __restrict__ c2w,
                         u32* __restrict__ wcv)
{
  int e = blockIdx.x*256 + threadIdx.x;
  if (e >= 82944) return;
  int conv = e / 41472, r = e - conv*41472;
  int tap = r / 4608, r2 = r - tap*4608;
  int jk = r2 >> 8;              // (j*3+ks) 0..17
  int lane = (r2 >> 2) & 63;
  int q = r2 & 3;
  int j = jk/3, ks = jk - j*3;
  int n = j*16 + (lane & 15);
  int k = ks*32 + (lane >> 4)*8 + 2*q;
  const float* s = conv ? c2w : c1w;
  wcv[e] = pack2(s[(n*96 + k)*9 + tap], s[(n*96 + k + 1)*9 + tap]);
}

// ---------------------------------------------------------------------------
// K1: fused windowed attention (3 blocks/CU, 43KB LDS) — unchanged from R13.
// ---------------------------------------------------------------------------
__global__ __launch_bounds__(256,3) void attn_k(
    const float* __restrict__ x, const float* __restrict__ ndwi,
    const float* __restrict__ n1g, const float* __restrict__ n1b,
    const u32* __restrict__ w8q, const float* __restrict__ qb,
    const u32* __restrict__ w8p, const float* __restrict__ pb,
    const float* __restrict__ rpbt, u16* __restrict__ x1o)
{
  __shared__ u32 xp[49*49];
  __shared__ u32 qp[49*49];
  __shared__ u32 kp[49*49];
  __shared__ u16 vpT[96*50];
  __shared__ float rpb[8*169];
  __shared__ float mw[49];
  const int tid = threadIdx.x;
  const int blk = blockIdx.x;
  const int b = blk >> 10, wy = (blk>>5)&31, wx = blk&31;
  const int wv_ = __builtin_amdgcn_readfirstlane(tid >> 6);
  const int ln  = tid & 63;
  const int lnc = ln < 49 ? ln : 48;

  for (int i = tid; i < 1352; i += 256){
    int h = i/169, idx = i - h*169;
    rpb[i] = rpbt[idx*8 + h];
  }
  for (int i = tid; i < 96; i += 256) vpT[i*50 + 49] = 0;

  if (tid < 196){
    const int t = tid >> 2, p = tid & 3;
    const int ty = t/7, tx = t - (t/7)*7;
    int sy = wy*7 + ty - 3; if (sy < 0) sy += 224;
    int sx = wx*7 + tx - 3; if (sx < 0) sx += 224;
    const size_t rowb = ((size_t)((b*224 + sy)*224 + sx))*96;
    const float* xr = x + rowb + p*24;
    float c[24];
    #pragma unroll
    for (int q = 0; q < 6; q++){
      float4 v = ((const float4*)xr)[q];
      c[q*4+0]=v.x; c[q*4+1]=v.y; c[q*4+2]=v.z; c[q*4+3]=v.w;
    }
    if (p == 0) mw[t] = ndwi[(size_t)b*50176 + sy*224 + sx];
    float s = 0.f, s2 = 0.f;
    #pragma unroll
    for (int j = 0; j < 24; j++){ s += c[j]; s2 += c[j]*c[j]; }
    s  += __shfl_xor(s, 1);  s  += __shfl_xor(s, 2);
    s2 += __shfl_xor(s2, 1); s2 += __shfl_xor(s2, 2);
    float m = s*(1.f/96.f);
    float rs = rsqrtf(s2*(1.f/96.f) - m*m + 1e-5f);
    #pragma unroll
    for (int jj = 0; jj < 12; jj++){
      float a = (c[2*jj]  -m)*rs*n1g[p*24+2*jj]   + n1b[p*24+2*jj];
      float d = (c[2*jj+1]-m)*rs*n1g[p*24+2*jj+1] + n1b[p*24+2*jj+1];
      xp[t*49 + p*12 + jj] = pack2(a, d);
    }
  }
  __syncthreads();

  for (int ogi = 0; ogi < 9; ogi++){
    const int og = wv_*9 + ogi;
    const int o0 = og*8;
    const u32* wrow = w8q + og*384;
    float acc[8];
    #pragma unroll
    for (int k = 0; k < 8; k++) acc[k] = qb[o0+k];
    #pragma unroll 4
    for (int cp = 0; cp < 48; cp++){
      u32 xv = xp[lnc*49 + cp];
      uint4 wa = *(const uint4*)(wrow + cp*8);
      uint4 wb = *(const uint4*)(wrow + cp*8 + 4);
      acc[0] = dot2bf(xv, wa.x, acc[0]); acc[1] = dot2bf(xv, wa.y, acc[1]);
      acc[2] = dot2bf(xv, wa.z, acc[2]); acc[3] = dot2bf(xv, wa.w, acc[3]);
      acc[4] = dot2bf(xv, wb.x, acc[4]); acc[5] = dot2bf(xv, wb.y, acc[5]);
      acc[6] = dot2bf(xv, wb.z, acc[6]); acc[7] = dot2bf(xv, wb.w, acc[7]);
    }
    if (ln < 49){
      if (og < 12){
        const float S = 0.28867513459481287f;
        #pragma unroll
        for (int m = 0; m < 4; m++) qp[ln*49 + og*4 + m] = pack2(acc[2*m]*S, acc[2*m+1]*S);
      } else if (og < 24){
        #pragma unroll
        for (int m = 0; m < 4; m++) kp[ln*49 + (og-12)*4 + m] = pack2(acc[2*m], acc[2*m+1]);
      } else {
        const int o0v = (og-24)*8;
        #pragma unroll
        for (int k = 0; k < 8; k++) vpT[(o0v+k)*50 + ln] = f2bf(acc[k]);
      }
    }
  }
  __syncthreads();

  for (int task = tid; task < 392; task += 256){
    int h = task/49, i = task - (task/49)*49;
    int iy = i/7, ix = i - (i/7)*7;
    u32 qv[6];
    #pragma unroll
    for (int e = 0; e < 6; e++) qv[e] = qp[i*49 + h*6 + e];
    const float* rb = &rpb[h*169 + (iy+6)*13 + (ix+6)];
    float s[49]; float mx = -1e30f;
    float mi = mw[i];
    int j = 0;
    #pragma unroll
    for (int jy = 0; jy < 7; jy++)
    #pragma unroll
    for (int jx = 0; jx < 7; jx++, j++){
      const u32* kr = &kp[j*49 + h*6];
      float a = rb[-(jy*13+jx)];
      a = dot2bf(qv[0], kr[0], a); a = dot2bf(qv[1], kr[1], a);
      a = dot2bf(qv[2], kr[2], a); a = dot2bf(qv[3], kr[3], a);
      a = dot2bf(qv[4], kr[4], a); a = dot2bf(qv[5], kr[5], a);
      a = (mi != mw[j]) ? a - 100.f : a;
      s[j] = a; mx = fmaxf(mx, a);
    }
    float l = 0.f;
    #pragma unroll
    for (int jj = 0; jj < 49; jj++){ float p = __expf(s[jj]-mx); s[jj] = p; l += p; }
    float rl = 1.f/l;
    u32 pp[25];
    #pragma unroll
    for (int e = 0; e < 24; e++)
      pp[e] = (__builtin_bit_cast(u32, s[2*e]) >> 16)
            | (__builtin_bit_cast(u32, s[2*e+1]) & 0xffff0000u);
    pp[24] = __builtin_bit_cast(u32, s[48]) >> 16;
    float o[12];
    #pragma unroll
    for (int d = 0; d < 12; d++){
      const u32* vr = (const u32*)(vpT + (h*12+d)*50);
      float od = 0.f;
      #pragma unroll
      for (int e = 0; e < 25; e++) od = dot2bf(pp[e], vr[e], od);
      o[d] = od*rl;
    }
    #pragma unroll
    for (int m = 0; m < 6; m++) xp[i*49 + h*6 + m] = pack2(o[2*m], o[2*m+1]);
  }
  __syncthreads();

  for (int ogi = 0; ogi < 3; ogi++){
    const int og = wv_*3 + ogi;
    const int o0 = og*8;
    const u32* wrow = w8p + og*384;
    float acc[8];
    #pragma unroll
    for (int k = 0; k < 8; k++) acc[k] = pb[o0+k];
    #pragma unroll 4
    for (int cp = 0; cp < 48; cp++){
      u32 xv = xp[lnc*49 + cp];
      uint4 wa = *(const uint4*)(wrow + cp*8);
      uint4 wb = *(const uint4*)(wrow + cp*8 + 4);
      acc[0] = dot2bf(xv, wa.x, acc[0]); acc[1] = dot2bf(xv, wa.y, acc[1]);
      acc[2] = dot2bf(xv, wa.z, acc[2]); acc[3] = dot2bf(xv, wa.w, acc[3]);
      acc[4] = dot2bf(xv, wb.x, acc[4]); acc[5] = dot2bf(xv, wb.y, acc[5]);
      acc[6] = dot2bf(xv, wb.z, acc[6]); acc[7] = dot2bf(xv, wb.w, acc[7]);
    }
    if (ln < 49){
      #pragma unroll
      for (int m = 0; m < 4; m++) qp[ln*49 + og*4 + m] = pack2(acc[2*m], acc[2*m+1]);
    }
  }
  __syncthreads();

  for (int e = tid; e < 588; e += 256){
    int t = e/12, g = e - (e/12)*12;
    int ty = t/7, tx = t - (t/7)*7;
    int dy = wy*7 + ty - 4; if (dy < 0) dy += 224;
    int dx = wx*7 + tx - 4; if (dx < 0) dx += 224;
    size_t base = ((size_t)((b*224+dy)*224+dx))*96 + g*8;
    float4 r0 = *(const float4*)(x + base);
    float4 r1 = *(const float4*)(x + base + 4);
    const u32* pr = &qp[t*49 + g*4];
    uint4 ov;
    ov.x = pack2(lo16(pr[0])+r0.x, hi16(pr[0])+r0.y);
    ov.y = pack2(lo16(pr[1])+r0.z, hi16(pr[1])+r0.w);
    ov.z = pack2(lo16(pr[2])+r1.x, hi16(pr[2])+r1.y);
    ov.w = pack2(lo16(pr[3])+r1.z, hi16(pr[3])+r1.w);
    *(uint4*)(x1o + base) = ov;
  }
}

// ---------------------------------------------------------------------------
// K2: fused LN2 + MLP + residual — MFMA edition (unchanged from R13).
// ---------------------------------------------------------------------------
__global__ __launch_bounds__(256,2) void mlp_k(
    const u16* __restrict__ x1, const float* __restrict__ w1, const float* __restrict__ b1,
    const float* __restrict__ w2, const float* __restrict__ b2,
    const float* __restrict__ g2, const float* __restrict__ bb2,
    float* __restrict__ x2o)
{
  __shared__ __align__(16) u16 xA [4*3*64*8];
  __shared__ __align__(16) u16 hA [4*3*64*8];
  __shared__ __align__(16) u16 w1f[6*3*64*8];
  __shared__ __align__(16) u16 w2f[6*3*64*8];
  const int tid = threadIdx.x;
  const size_t t0 = (size_t)blockIdx.x * 64;
  const int wvM = tid >> 6;
  const int ln  = tid & 63;
  const int colv = ln & 15, rgrp = ln >> 4;

  {
    const int t = tid >> 2, p = tid & 3;
    const u16* xr = x1 + (t0 + t)*96 + p*24;
    float c[24];
    #pragma unroll
    for (int q = 0; q < 3; q++){
      uint4 v = ((const uint4*)xr)[q];
      c[q*8+0]=lo16(v.x); c[q*8+1]=hi16(v.x);
      c[q*8+2]=lo16(v.y); c[q*8+3]=hi16(v.y);
      c[q*8+4]=lo16(v.z); c[q*8+5]=hi16(v.z);
      c[q*8+6]=lo16(v.w); c[q*8+7]=hi16(v.w);
    }
    float s = 0.f, s2 = 0.f;
    #pragma unroll
    for (int j = 0; j < 24; j++){ s += c[j]; s2 += c[j]*c[j]; }
    s  += __shfl_xor(s, 1);  s  += __shfl_xor(s, 2);
    s2 += __shfl_xor(s2, 1); s2 += __shfl_xor(s2, 2);
    float m = s*(1.f/96.f);
    float rs = rsqrtf(s2*(1.f/96.f) - m*m + 1e-5f);
    const int mt = t >> 4, row = t & 15;
    #pragma unroll
    for (int jj = 0; jj < 12; jj++){
      int k = p*24 + 2*jj;
      float a = (c[2*jj]  -m)*rs*g2[k]   + bb2[k];
      float d = (c[2*jj+1]-m)*rs*g2[k+1] + bb2[k+1];
      int ks = k >> 5, g = (k & 31) >> 3, i = k & 7;
      *(u32*)&xA[(((mt*3 + ks)*64 + g*16 + row)<<3) + i] = pack2(a, d);
    }
  }

  f32x4 acc2[6];
  #pragma unroll
  for (int j = 0; j < 6; j++) acc2[j] = (f32x4){0.f,0.f,0.f,0.f};

  for (int q = 0; q < 4; q++){
    __syncthreads();
    for (int e = tid; e < 4608; e += 256){
      int n = e/48, cp = e - (e/48)*48, k = cp*2;
      int ks = k >> 5, g = (k & 31) >> 3, i = k & 7;
      int fidx = ((((n>>4)*3 + ks)*64 + g*16 + (n&15))<<3) + i;
      {
        const float* s = w1 + (size_t)(q*96 + n)*96 + k;
        *(u32*)&w1f[fidx] = pack2(s[0], s[1]);
      }
      {
        const float* s = w2 + (size_t)n*384 + q*96 + k;
        *(u32*)&w2f[fidx] = pack2(s[0], s[1]);
      }
    }
    __syncthreads();

    bf16x8 af[3];
    #pragma unroll
    for (int ks = 0; ks < 3; ks++)
      af[ks] = *(const bf16x8*)&xA[((wvM*3 + ks)*64 + ln)*8];
    #pragma unroll
    for (int j = 0; j < 6; j++){
      f32x4 c = (f32x4){0.f,0.f,0.f,0.f};
      #pragma unroll
      for (int ks = 0; ks < 3; ks++){
        bf16x8 bfv = *(const bf16x8*)&w1f[((j*3 + ks)*64 + ln)*8];
        c = __builtin_amdgcn_mfma_f32_16x16x32_bf16(af[ks], bfv, c, 0, 0, 0);
      }
      const float bv = b1[q*96 + j*16 + colv];
      const int kq = j*16 + colv;
      const int ks2 = kq >> 5, gg = (kq & 31) >> 3, ii = kq & 7;
      u16* hdst = &hA[(((wvM*3 + ks2)*64 + gg*16)<<3) + ii];
      #pragma unroll
      for (int r = 0; r < 4; r++){
        int rowh = rgrp*4 + r;
        hdst[rowh*8] = f2bf(gelu(c[r] + bv));
      }
    }
    __syncthreads();

    bf16x8 hf[3];
    #pragma unroll
    for (int ks = 0; ks < 3; ks++)
      hf[ks] = *(const bf16x8*)&hA[((wvM*3 + ks)*64 + ln)*8];
    #pragma unroll
    for (int j = 0; j < 6; j++){
      #pragma unroll
      for (int ks = 0; ks < 3; ks++){
        bf16x8 bfv = *(const bf16x8*)&w2f[((j*3 + ks)*64 + ln)*8];
        acc2[j] = __builtin_amdgcn_mfma_f32_16x16x32_bf16(hf[ks], bfv, acc2[j], 0, 0, 0);
      }
    }
  }

  #pragma unroll
  for (int j = 0; j < 6; j++){
    const int oc = j*16 + colv;
    const float bv = b2[oc];
    #pragma unroll
    for (int r = 0; r < 4; r++){
      size_t tok = t0 + wvM*16 + rgrp*4 + r;
      x2o[tok*96 + oc] = acc2[j][r] + bv + bf2f(x1[tok*96 + oc]);
    }
  }
}

// ---------------------------------------------------------------------------
// K3: MFMA implicit-GEMM 3x3 conv (dil DIL) + bias + BN + GELU
// [+ LN3 preprocess] [+ residual]. Block = 8x8 output pixels, 4 waves;
// 9 taps accumulate into acc[6]. Input tile pixel-major, 104-u16 stride
// (aligned b128 A-frag reads). Weights are pre-packed B-fragments (wpk)
// with in-kernel OIHW fallback.
// ---------------------------------------------------------------------------
template<int DIL, bool LN3, bool FINAL>
__global__ __launch_bounds__(256,3) void convm_k(
    const void* __restrict__ srcv, const u32* __restrict__ wpk,
    const float* __restrict__ wOIHW,
    const float* __restrict__ cb, const float* __restrict__ bng, const float* __restrict__ bnb,
    const float* __restrict__ bnm, const float* __restrict__ bnv,
    const float* __restrict__ g3, const float* __restrict__ b3,
    const float* resid, void* dstv)
{
  constexpr int SY = 8 + 2*DIL, SX = 8 + 2*DIL, NPIX = SY*SX;
  __shared__ __align__(16) u16 inT[NPIX*104];   // [pixel][96ch + pad]
  __shared__ __align__(16) u32 wfr[4608];       // one tap of B-fragments
  const int tid = threadIdx.x;
  const int bx = blockIdx.x*8, by = blockIdx.y*8, b = blockIdx.z;
  const int gy0 = by - DIL, gx0 = bx - DIL;

  // stage input tile (f32 src for conv1, bf16 src for conv2); halo -> 0
  for (int e = tid; e < NPIX*48; e += 256){
    int p = e/48, c2 = e - (e/48)*48;
    int y = p/SX, xx = p - (p/SX)*SX;
    int gy = gy0+y, gx = gx0+xx;
    u32 v = 0;
    if (gy >= 0 && gy < 224 && gx >= 0 && gx < 224){
      size_t idx = ((size_t)((b*224+gy)*224+gx))*96 + c2*2;
      if (LN3){
        float2 rd = *(const float2*)((const float*)srcv + idx);
        v = pack2(rd.x, rd.y);
      } else {
        v = *(const u32*)((const u16*)srcv + idx);
      }
    }
    *(u32*)&inT[p*104 + c2*2] = v;
  }
  if (LN3){
    __syncthreads();
    // per-pixel LayerNorm: 2 threads/pixel (48 ch each), shfl-xor(1) reduce.
    if (tid < 2*NPIX){
      const int p = tid >> 1, half = tid & 1;
      int y = p/SX, xx = p - (p/SX)*SX;
      int gy = gy0+y, gx = gx0+xx;
      if (gy >= 0 && gy < 224 && gx >= 0 && gx < 224){
        u32* row = (u32*)&inT[p*104] + half*24;
        float c[48];
        #pragma unroll
        for (int i = 0; i < 24; i++){ u32 v = row[i]; c[2*i] = lo16(v); c[2*i+1] = hi16(v); }
        float s = 0.f, s2 = 0.f;
        #pragma unroll
        for (int i = 0; i < 48; i++){ s += c[i]; s2 += c[i]*c[i]; }
        s  += __shfl_xor(s, 1);
        s2 += __shfl_xor(s2, 1);
        float m = s*(1.f/96.f);
        float rs = rsqrtf(s2*(1.f/96.f) - m*m + 1e-5f);
        const int cbase = half*48;
        #pragma unroll
        for (int i = 0; i < 24; i++){
          float a = (c[2*i]  -m)*rs*g3[cbase+2*i]   + b3[cbase+2*i];
          float d = (c[2*i+1]-m)*rs*g3[cbase+2*i+1] + b3[cbase+2*i+1];
          row[i] = pack2(a, d);
        }
      }
    }
  }

  const int wvM = tid >> 6, ln = tid & 63;
  const int colv = ln & 15, rgrp = ln >> 4;
  const int arow = ln & 15;                       // A-frag row = pixel-in-tile
  const int aoy = wvM*2 + (arow >> 3), aox = arow & 7;

  f32x4 acc[6];
  #pragma unroll
  for (int j = 0; j < 6; j++) acc[j] = (f32x4){0.f,0.f,0.f,0.f};

  for (int tap = 0; tap < 9; tap++){
    const int ky = tap/3, kx = tap - (tap/3)*3;
    __syncthreads();
    if (wpk){
      const u32* wsrc = wpk + tap*4608;
      for (int e = tid; e < 4608; e += 256) wfr[e] = wsrc[e];
    } else {
      for (int e = tid; e < 4608; e += 256){
        int jk = e >> 8, lane = (e >> 2) & 63, q = e & 3;
        int j = jk/3, ks = jk - j*3;
        int n = j*16 + (lane & 15);
        int k = ks*32 + (lane >> 4)*8 + 2*q;
        wfr[e] = pack2(wOIHW[(n*96 + k)*9 + tap], wOIHW[(n*96 + k + 1)*9 + tap]);
      }
    }
    __syncthreads();
    const int p_in = (aoy + ky*DIL)*SX + aox + kx*DIL;
    bf16x8 af[3];
    #pragma unroll
    for (int ks = 0; ks < 3; ks++)
      af[ks] = *(const bf16x8*)&inT[p_in*104 + ks*32 + rgrp*8];
    #pragma unroll
    for (int j = 0; j < 6; j++){
      #pragma unroll
      for (int ks = 0; ks < 3; ks++){
        bf16x8 bfv = *(const bf16x8*)((const u16*)wfr + ((j*3 + ks)*64 + ln)*8);
        acc[j] = __builtin_amdgcn_mfma_f32_16x16x32_bf16(af[ks], bfv, acc[j], 0, 0, 0);
      }
    }
  }

  // epilogue: bias + BN + GELU (+ residual), D: col=oc-in-jtile, row=pixel
  #pragma unroll
  for (int j = 0; j < 6; j++){
    const int oc = j*16 + colv;
    const float sc = bng[oc]*rsqrtf(bnv[oc]+1e-5f);
    const float mm = bnm[oc], bb = bnb[oc], cbv = cb[oc];
    #pragma unroll
    for (int r = 0; r < 4; r++){
      const int rowm = rgrp*4 + r;
      const int gy = by + wvM*2 + (rowm >> 3), gx = bx + (rowm & 7);
      size_t idx = ((size_t)((b*224+gy)*224+gx))*96 + oc;
      float t = (acc[j][r] + cbv - mm)*sc + bb;
      float o = gelu(t);
      if (FINAL){
        ((float*)dstv)[idx] = o + resid[idx];
      } else {
        ((u16*)dstv)[idx] = f2bf(o);
      }
    }
  }
}

// ---------------------------------------------------------------------------
extern "C" void kernel_launch(void* const* d_in, const int* in_sizes, int n_in,
                              void* d_out, int out_size, void* d_ws, size_t ws_size,
                              hipStream_t stream)
{
  const float* x    = (const float*)d_in[0];
  const float* ndwi = (const float*)d_in[1];
  const float* n1g  = (const float*)d_in[2];
  const float* n1b  = (const float*)d_in[3];
  const float* qkvw = (const float*)d_in[4];
  const float* qkvb = (const float*)d_in[5];
  const float* projw= (const float*)d_in[6];
  const float* projb= (const float*)d_in[7];
  const float* rpbt = (const float*)d_in[8];
  const float* n2g  = (const float*)d_in[9];
  const float* n2b  = (const float*)d_in[10];
  const float* w1   = (const float*)d_in[11];
  const float* b1   = (const float*)d_in[12];
  const float* w2   = (const float*)d_in[13];
  const float* b2   = (const float*)d_in[14];
  const float* n3g  = (const float*)d_in[15];
  const float* n3b  = (const float*)d_in[16];
  const float* c1w  = (const float*)d_in[17];
  const float* c1b  = (const float*)d_in[18];
  const float* bn1g = (const float*)d_in[19];
  const float* bn1b = (const float*)d_in[20];
  const float* bn1m = (const float*)d_in[21];
  const float* bn1v = (const float*)d_in[22];
  const float* c2w  = (const float*)d_in[23];
  const float* c2b  = (const float*)d_in[24];
  const float* bn2g = (const float*)d_in[25];
  const float* bn2b = (const float*)d_in[26];
  const float* bn2m = (const float*)d_in[27];
  const float* bn2v = (const float*)d_in[28];

  int B = out_size / (224*224*96);
  if (B < 1 || B > 64) B = 4;
  const size_t elems = (size_t)B*224*224*96;

  u16*   wsA = (u16*)d_ws;
  u32*   w8q = (u32*)d_out;
  u32*   w8p = w8q + 13824;
  float* xo  = (float*)d_out;
  u32*   wcv = nullptr;
  if (ws_size >= elems*sizeof(u16) + 82944*sizeof(u32))
    wcv = (u32*)(wsA + elems);

  wprep_k<<<dim3(72), dim3(256), 0, stream>>>(qkvw, projw, w8q, w8p);
  if (wcv) wprep_cv<<<dim3(324), dim3(256), 0, stream>>>(c1w, c2w, wcv);
  attn_k<<<dim3(B*1024), dim3(256), 0, stream>>>(x, ndwi, n1g, n1b, w8q, qkvb, w8p, projb, rpbt, wsA);
  mlp_k<<<dim3(B*784), dim3(256), 0, stream>>>(wsA, w1, b1, w2, b2, n2g, n2b, xo);
  convm_k<1,true ,false><<<dim3(28,28,B), dim3(256), 0, stream>>>(
      xo,  wcv,               c1w, c1b, bn1g, bn1b, bn1m, bn1v, n3g, n3b, nullptr, wsA);
  convm_k<2,false,true ><<<dim3(28,28,B), dim3(256), 0, stream>>>(
      wsA, wcv ? wcv+41472 : nullptr, c2w, c2b, bn2g, bn2b, bn2m, bn2v, nullptr, nullptr, xo, xo);
}

// Round 15
// 633.895 us; speedup vs baseline: 2.5095x; 1.2750x over previous
//
#include <hip/hip_runtime.h>
#include <hip/hip_bf16.h>

typedef unsigned int u32;
typedef unsigned short u16;

#define DF __device__ __forceinline__

DF float bf2f(u16 v){ u32 t = ((u32)v)<<16; return __builtin_bit_cast(float, t); }
DF u16 f2bf(float f){
  u32 t = __builtin_bit_cast(u32, f);
  t += 0x7fffu + ((t>>16)&1u);
  return (u16)(t>>16);
}
DF float lo16(u32 p){ return __builtin_bit_cast(float, p<<16); }
DF float hi16(u32 p){ return __builtin_bit_cast(float, p & 0xffff0000u); }
DF u32 pack2(float a, float b){ return (u32)f2bf(a) | (((u32)f2bf(b))<<16); }
DF float gelu(float x){ return 0.5f*x*(1.0f+erff(x*0.70710678118654752f)); }

#if defined(__has_builtin)
#if __has_builtin(__builtin_amdgcn_fdot2_f32_bf16)
#define HAVE_DOT2 1
#endif
#endif
#ifdef HAVE_DOT2
DF float dot2bf(u32 a, u32 b, float c){
  typedef __bf16 b2 __attribute__((ext_vector_type(2)));
  return __builtin_amdgcn_fdot2_f32_bf16(__builtin_bit_cast(b2,a), __builtin_bit_cast(b2,b), c, false);
}
#else
DF float dot2bf(u32 a, u32 b, float c){
  float d;
  asm("v_dot2_f32_bf16 %0, %1, %2, %3" : "=v"(d) : "v"(a), "v"(b), "v"(c));
  return d;
}
#endif

typedef __attribute__((ext_vector_type(8))) __bf16 bf16x8;
typedef __attribute__((ext_vector_type(4))) float f32x4;

// ---------------------------------------------------------------------------
// K0: pack qkv/proj weights as MFMA B-FRAGMENTS (front of d_out).
// w8q: [jt(18)][ks(3)][lane(64)][4 u32]; n=jt*16+(lane&15) (=output ch),
// k=ks*32+(lane>>4)*8+2q. w8p: [6][3][64][4] likewise.
// ---------------------------------------------------------------------------
__global__ void wprep_k(const float* __restrict__ qkvw, const float* __restrict__ projw,
                        u32* __restrict__ w8q, u32* __restrict__ w8p)
{
  int e = blockIdx.x*256 + threadIdx.x;
  if (e < 13824){
    int jk = e >> 8, lane = (e >> 2) & 63, q = e & 3;
    int jt = jk/3, ks = jk - jt*3;
    int n = jt*16 + (lane & 15);
    int k = ks*32 + (lane >> 4)*8 + 2*q;
    w8q[e] = pack2(qkvw[n*96 + k], qkvw[n*96 + k + 1]);
  } else if (e < 18432){
    int r2 = e - 13824;
    int jk = r2 >> 8, lane = (r2 >> 2) & 63, q = r2 & 3;
    int jt = jk/3, ks = jk - jt*3;
    int n = jt*16 + (lane & 15);
    int k = ks*32 + (lane >> 4)*8 + 2*q;
    w8p[r2] = pack2(projw[n*96 + k], projw[n*96 + k + 1]);
  }
}

// ---------------------------------------------------------------------------
// K0b: pack conv weights as MFMA B-fragments into ws tail (unchanged R14).
// ---------------------------------------------------------------------------
__global__ void wprep_cv(const float* __restrict__ c1w, const float* __restrict__ c2w,
                         u32* __restrict__ wcv)
{
  int e = blockIdx.x*256 + threadIdx.x;
  if (e >= 82944) return;
  int conv = e / 41472, r = e - conv*41472;
  int tap = r / 4608, r2 = r - tap*4608;
  int jk = r2 >> 8;
  int lane = (r2 >> 2) & 63;
  int q = r2 & 3;
  int j = jk/3, ks = jk - j*3;
  int n = j*16 + (lane & 15);
  int k = ks*32 + (lane >> 4)*8 + 2*q;
  const float* s = conv ? c2w : c1w;
  wcv[e] = pack2(s[(n*96 + k)*9 + tap], s[(n*96 + k + 1)*9 + tap]);
}

// ---------------------------------------------------------------------------
// K1: fused windowed attention — QKV/proj via MFMA, softmax core via dot2.
// LDS ~46.7KB -> 3 blocks/CU.
// ---------------------------------------------------------------------------
__global__ __launch_bounds__(256,3) void attn_k(
    const float* __restrict__ x, const float* __restrict__ ndwi,
    const float* __restrict__ n1g, const float* __restrict__ n1b,
    const u32* __restrict__ w8q, const float* __restrict__ qb,
    const u32* __restrict__ w8p, const float* __restrict__ pb,
    const float* __restrict__ rpbt, u16* __restrict__ x1o)
{
  __shared__ __align__(16) u16 xA[4*3*64*8];  // x A-frags; later attn-out A-frags
  __shared__ u32 qp[49*49];    // q as u16[49][98]; later proj-out
  __shared__ u32 kp[49*49];    // k as u16[49][98]
  __shared__ u16 vpT[96*50];   // v transposed [d][j]
  __shared__ float rpb[8*169];
  __shared__ float mw[49];
  const int tid = threadIdx.x;
  const int blk = blockIdx.x;
  const int b = blk >> 10, wy = (blk>>5)&31, wx = blk&31;
  const int wv_ = __builtin_amdgcn_readfirstlane(tid >> 6);
  const int ln  = tid & 63;
  const int colv = ln & 15, rgrp = ln >> 4;

  for (int i = tid; i < 1352; i += 256){
    int h = i/169, idx = i - h*169;
    rpb[i] = rpbt[idx*8 + h];
  }
  for (int i = tid; i < 96; i += 256) vpT[i*50 + 49] = 0;

  // LN1 straight from global -> xA fragments (4 lanes per token)
  if (tid < 196){
    const int t = tid >> 2, p = tid & 3;
    const int ty = t/7, tx = t - (t/7)*7;
    int sy = wy*7 + ty - 3; if (sy < 0) sy += 224;
    int sx = wx*7 + tx - 3; if (sx < 0) sx += 224;
    const size_t rowb = ((size_t)((b*224 + sy)*224 + sx))*96;
    const float* xr = x + rowb + p*24;
    float c[24];
    #pragma unroll
    for (int q = 0; q < 6; q++){
      float4 v = ((const float4*)xr)[q];
      c[q*4+0]=v.x; c[q*4+1]=v.y; c[q*4+2]=v.z; c[q*4+3]=v.w;
    }
    if (p == 0) mw[t] = ndwi[(size_t)b*50176 + sy*224 + sx];
    float s = 0.f, s2 = 0.f;
    #pragma unroll
    for (int j = 0; j < 24; j++){ s += c[j]; s2 += c[j]*c[j]; }
    s  += __shfl_xor(s, 1);  s  += __shfl_xor(s, 2);
    s2 += __shfl_xor(s2, 1); s2 += __shfl_xor(s2, 2);
    float m = s*(1.f/96.f);
    float rs = rsqrtf(s2*(1.f/96.f) - m*m + 1e-5f);
    const int mt = t >> 4, row = t & 15;
    #pragma unroll
    for (int jj = 0; jj < 12; jj++){
      int k = p*24 + 2*jj;
      float a = (c[2*jj]  -m)*rs*n1g[k]   + n1b[k];
      float d = (c[2*jj+1]-m)*rs*n1g[k+1] + n1b[k+1];
      int ks = k >> 5, g = (k & 31) >> 3, i = k & 7;
      *(u32*)&xA[(((mt*3 + ks)*64 + g*16 + row)<<3) + i] = pack2(a, d);
    }
  }
  __syncthreads();

  // QKV via MFMA: wave = m-tile of 16 tokens; B-frags from L2-resident global
  {
    bf16x8 af[3];
    #pragma unroll
    for (int ks = 0; ks < 3; ks++)
      af[ks] = *(const bf16x8*)&xA[((wv_*3 + ks)*64 + ln)*8];
    u16* qpu = (u16*)qp;
    u16* kpu = (u16*)kp;
    const float S = 0.28867513459481287f;
    for (int jt = 0; jt < 18; jt++){
      f32x4 c = (f32x4){0.f,0.f,0.f,0.f};
      #pragma unroll
      for (int ks = 0; ks < 3; ks++){
        bf16x8 bw = *(const bf16x8*)(w8q + ((jt*3 + ks)*64 + ln)*4);
        c = __builtin_amdgcn_mfma_f32_16x16x32_bf16(af[ks], bw, c, 0, 0, 0);
      }
      const int oc = jt*16 + colv;
      const float bv = qb[oc];
      #pragma unroll
      for (int r = 0; r < 4; r++){
        int tok = wv_*16 + rgrp*4 + r;
        if (tok < 49){
          float v = c[r] + bv;
          if (oc < 96)       qpu[tok*98 + oc]        = f2bf(v*S);
          else if (oc < 192) kpu[tok*98 + (oc-96)]   = f2bf(v);
          else               vpT[(oc-192)*50 + tok]  = f2bf(v);
        }
      }
    }
  }
  __syncthreads();

  // attention core (dot2 softmax); output -> xA as A-fragments
  for (int task = tid; task < 392; task += 256){
    int h = task/49, i = task - (task/49)*49;
    int iy = i/7, ix = i - (i/7)*7;
    u32 qv[6];
    #pragma unroll
    for (int e = 0; e < 6; e++) qv[e] = qp[i*49 + h*6 + e];
    const float* rb = &rpb[h*169 + (iy+6)*13 + (ix+6)];
    float s[49]; float mx = -1e30f;
    float mi = mw[i];
    int j = 0;
    #pragma unroll
    for (int jy = 0; jy < 7; jy++)
    #pragma unroll
    for (int jx = 0; jx < 7; jx++, j++){
      const u32* kr = &kp[j*49 + h*6];
      float a = rb[-(jy*13+jx)];
      a = dot2bf(qv[0], kr[0], a); a = dot2bf(qv[1], kr[1], a);
      a = dot2bf(qv[2], kr[2], a); a = dot2bf(qv[3], kr[3], a);
      a = dot2bf(qv[4], kr[4], a); a = dot2bf(qv[5], kr[5], a);
      a = (mi != mw[j]) ? a - 100.f : a;
      s[j] = a; mx = fmaxf(mx, a);
    }
    float l = 0.f;
    #pragma unroll
    for (int jj = 0; jj < 49; jj++){ float p = __expf(s[jj]-mx); s[jj] = p; l += p; }
    float rl = 1.f/l;
    u32 pp[25];
    #pragma unroll
    for (int e = 0; e < 24; e++)
      pp[e] = (__builtin_bit_cast(u32, s[2*e]) >> 16)
            | (__builtin_bit_cast(u32, s[2*e+1]) & 0xffff0000u);
    pp[24] = __builtin_bit_cast(u32, s[48]) >> 16;
    float o[12];
    #pragma unroll
    for (int d = 0; d < 12; d++){
      const u32* vr = (const u32*)(vpT + (h*12+d)*50);
      float od = 0.f;
      #pragma unroll
      for (int e = 0; e < 25; e++) od = dot2bf(pp[e], vr[e], od);
      o[d] = od*rl;
    }
    const int mt2 = i >> 4, row2 = i & 15;
    #pragma unroll
    for (int m = 0; m < 6; m++){
      int k = h*12 + 2*m;
      int ks = k >> 5, g = (k & 31) >> 3, ii = k & 7;
      *(u32*)&xA[(((mt2*3 + ks)*64 + g*16 + row2)<<3) + ii] = pack2(o[2*m], o[2*m+1]);
    }
  }
  __syncthreads();

  // proj via MFMA -> qp (u16, dead after QK^T)
  {
    bf16x8 af[3];
    #pragma unroll
    for (int ks = 0; ks < 3; ks++)
      af[ks] = *(const bf16x8*)&xA[((wv_*3 + ks)*64 + ln)*8];
    u16* qpu = (u16*)qp;
    for (int jt = 0; jt < 6; jt++){
      f32x4 c = (f32x4){0.f,0.f,0.f,0.f};
      #pragma unroll
      for (int ks = 0; ks < 3; ks++){
        bf16x8 bw = *(const bf16x8*)(w8p + ((jt*3 + ks)*64 + ln)*4);
        c = __builtin_amdgcn_mfma_f32_16x16x32_bf16(af[ks], bw, c, 0, 0, 0);
      }
      const int oc = jt*16 + colv;
      const float bv = pb[oc];
      #pragma unroll
      for (int r = 0; r < 4; r++){
        int tok = wv_*16 + rgrp*4 + r;
        if (tok < 49) qpu[tok*98 + oc] = f2bf(c[r] + bv);
      }
    }
  }
  __syncthreads();

  // write: reverse roll (-4) + residual (unchanged)
  for (int e = tid; e < 588; e += 256){
    int t = e/12, g = e - (e/12)*12;
    int ty = t/7, tx = t - (t/7)*7;
    int dy = wy*7 + ty - 4; if (dy < 0) dy += 224;
    int dx = wx*7 + tx - 4; if (dx < 0) dx += 224;
    size_t base = ((size_t)((b*224+dy)*224+dx))*96 + g*8;
    float4 r0 = *(const float4*)(x + base);
    float4 r1 = *(const float4*)(x + base + 4);
    const u32* pr = &qp[t*49 + g*4];
    uint4 ov;
    ov.x = pack2(lo16(pr[0])+r0.x, hi16(pr[0])+r0.y);
    ov.y = pack2(lo16(pr[1])+r0.z, hi16(pr[1])+r0.w);
    ov.z = pack2(lo16(pr[2])+r1.x, hi16(pr[2])+r1.y);
    ov.w = pack2(lo16(pr[3])+r1.z, hi16(pr[3])+r1.w);
    *(uint4*)(x1o + base) = ov;
  }
}

// ---------------------------------------------------------------------------
// K2: fused LN2 + MLP + residual — MFMA edition (unchanged from R14).
// ---------------------------------------------------------------------------
__global__ __launch_bounds__(256,2) void mlp_k(
    const u16* __restrict__ x1, const float* __restrict__ w1, const float* __restrict__ b1,
    const float* __restrict__ w2, const float* __restrict__ b2,
    const float* __restrict__ g2, const float* __restrict__ bb2,
    float* __restrict__ x2o)
{
  __shared__ __align__(16) u16 xA [4*3*64*8];
  __shared__ __align__(16) u16 hA [4*3*64*8];
  __shared__ __align__(16) u16 w1f[6*3*64*8];
  __shared__ __align__(16) u16 w2f[6*3*64*8];
  const int tid = threadIdx.x;
  const size_t t0 = (size_t)blockIdx.x * 64;
  const int wvM = tid >> 6;
  const int ln  = tid & 63;
  const int colv = ln & 15, rgrp = ln >> 4;

  {
    const int t = tid >> 2, p = tid & 3;
    const u16* xr = x1 + (t0 + t)*96 + p*24;
    float c[24];
    #pragma unroll
    for (int q = 0; q < 3; q++){
      uint4 v = ((const uint4*)xr)[q];
      c[q*8+0]=lo16(v.x); c[q*8+1]=hi16(v.x);
      c[q*8+2]=lo16(v.y); c[q*8+3]=hi16(v.y);
      c[q*8+4]=lo16(v.z); c[q*8+5]=hi16(v.z);
      c[q*8+6]=lo16(v.w); c[q*8+7]=hi16(v.w);
    }
    float s = 0.f, s2 = 0.f;
    #pragma unroll
    for (int j = 0; j < 24; j++){ s += c[j]; s2 += c[j]*c[j]; }
    s  += __shfl_xor(s, 1);  s  += __shfl_xor(s, 2);
    s2 += __shfl_xor(s2, 1); s2 += __shfl_xor(s2, 2);
    float m = s*(1.f/96.f);
    float rs = rsqrtf(s2*(1.f/96.f) - m*m + 1e-5f);
    const int mt = t >> 4, row = t & 15;
    #pragma unroll
    for (int jj = 0; jj < 12; jj++){
      int k = p*24 + 2*jj;
      float a = (c[2*jj]  -m)*rs*g2[k]   + bb2[k];
      float d = (c[2*jj+1]-m)*rs*g2[k+1] + bb2[k+1];
      int ks = k >> 5, g = (k & 31) >> 3, i = k & 7;
      *(u32*)&xA[(((mt*3 + ks)*64 + g*16 + row)<<3) + i] = pack2(a, d);
    }
  }

  f32x4 acc2[6];
  #pragma unroll
  for (int j = 0; j < 6; j++) acc2[j] = (f32x4){0.f,0.f,0.f,0.f};

  for (int q = 0; q < 4; q++){
    __syncthreads();
    for (int e = tid; e < 4608; e += 256){
      int n = e/48, cp = e - (e/48)*48, k = cp*2;
      int ks = k >> 5, g = (k & 31) >> 3, i = k & 7;
      int fidx = ((((n>>4)*3 + ks)*64 + g*16 + (n&15))<<3) + i;
      {
        const float* s = w1 + (size_t)(q*96 + n)*96 + k;
        *(u32*)&w1f[fidx] = pack2(s[0], s[1]);
      }
      {
        const float* s = w2 + (size_t)n*384 + q*96 + k;
        *(u32*)&w2f[fidx] = pack2(s[0], s[1]);
      }
    }
    __syncthreads();

    bf16x8 af[3];
    #pragma unroll
    for (int ks = 0; ks < 3; ks++)
      af[ks] = *(const bf16x8*)&xA[((wvM*3 + ks)*64 + ln)*8];
    #pragma unroll
    for (int j = 0; j < 6; j++){
      f32x4 c = (f32x4){0.f,0.f,0.f,0.f};
      #pragma unroll
      for (int ks = 0; ks < 3; ks++){
        bf16x8 bfv = *(const bf16x8*)&w1f[((j*3 + ks)*64 + ln)*8];
        c = __builtin_amdgcn_mfma_f32_16x16x32_bf16(af[ks], bfv, c, 0, 0, 0);
      }
      const float bv = b1[q*96 + j*16 + colv];
      const int kq = j*16 + colv;
      const int ks2 = kq >> 5, gg = (kq & 31) >> 3, ii = kq & 7;
      u16* hdst = &hA[(((wvM*3 + ks2)*64 + gg*16)<<3) + ii];
      #pragma unroll
      for (int r = 0; r < 4; r++){
        int rowh = rgrp*4 + r;
        hdst[rowh*8] = f2bf(gelu(c[r] + bv));
      }
    }
    __syncthreads();

    bf16x8 hf[3];
    #pragma unroll
    for (int ks = 0; ks < 3; ks++)
      hf[ks] = *(const bf16x8*)&hA[((wvM*3 + ks)*64 + ln)*8];
    #pragma unroll
    for (int j = 0; j < 6; j++){
      #pragma unroll
      for (int ks = 0; ks < 3; ks++){
        bf16x8 bfv = *(const bf16x8*)&w2f[((j*3 + ks)*64 + ln)*8];
        acc2[j] = __builtin_amdgcn_mfma_f32_16x16x32_bf16(hf[ks], bfv, acc2[j], 0, 0, 0);
      }
    }
  }

  #pragma unroll
  for (int j = 0; j < 6; j++){
    const int oc = j*16 + colv;
    const float bv = b2[oc];
    #pragma unroll
    for (int r = 0; r < 4; r++){
      size_t tok = t0 + wvM*16 + rgrp*4 + r;
      x2o[tok*96 + oc] = acc2[j][r] + bv + bf2f(x1[tok*96 + oc]);
    }
  }
}

// ---------------------------------------------------------------------------
// K3: MFMA implicit-GEMM 3x3 conv (unchanged from R14).
// ---------------------------------------------------------------------------
template<int DIL, bool LN3, bool FINAL>
__global__ __launch_bounds__(256,3) void convm_k(
    const void* __restrict__ srcv, const u32* __restrict__ wpk,
    const float* __restrict__ wOIHW,
    const float* __restrict__ cb, const float* __restrict__ bng, const float* __restrict__ bnb,
    const float* __restrict__ bnm, const float* __restrict__ bnv,
    const float* __restrict__ g3, const float* __restrict__ b3,
    const float* resid, void* dstv)
{
  constexpr int SY = 8 + 2*DIL, SX = 8 + 2*DIL, NPIX = SY*SX;
  __shared__ __align__(16) u16 inT[NPIX*104];
  __shared__ __align__(16) u32 wfr[4608];
  const int tid = threadIdx.x;
  const int bx = blockIdx.x*8, by = blockIdx.y*8, b = blockIdx.z;
  const int gy0 = by - DIL, gx0 = bx - DIL;

  for (int e = tid; e < NPIX*48; e += 256){
    int p = e/48, c2 = e - (e/48)*48;
    int y = p/SX, xx = p - (p/SX)*SX;
    int gy = gy0+y, gx = gx0+xx;
    u32 v = 0;
    if (gy >= 0 && gy < 224 && gx >= 0 && gx < 224){
      size_t idx = ((size_t)((b*224+gy)*224+gx))*96 + c2*2;
      if (LN3){
        float2 rd = *(const float2*)((const float*)srcv + idx);
        v = pack2(rd.x, rd.y);
      } else {
        v = *(const u32*)((const u16*)srcv + idx);
      }
    }
    *(u32*)&inT[p*104 + c2*2] = v;
  }
  if (LN3){
    __syncthreads();
    if (tid < 2*NPIX){
      const int p = tid >> 1, half = tid & 1;
      int y = p/SX, xx = p - (p/SX)*SX;
      int gy = gy0+y, gx = gx0+xx;
      if (gy >= 0 && gy < 224 && gx >= 0 && gx < 224){
        u32* row = (u32*)&inT[p*104] + half*24;
        float c[48];
        #pragma unroll
        for (int i = 0; i < 24; i++){ u32 v = row[i]; c[2*i] = lo16(v); c[2*i+1] = hi16(v); }
        float s = 0.f, s2 = 0.f;
        #pragma unroll
        for (int i = 0; i < 48; i++){ s += c[i]; s2 += c[i]*c[i]; }
        s  += __shfl_xor(s, 1);
        s2 += __shfl_xor(s2, 1);
        float m = s*(1.f/96.f);
        float rs = rsqrtf(s2*(1.f/96.f) - m*m + 1e-5f);
        const int cbase = half*48;
        #pragma unroll
        for (int i = 0; i < 24; i++){
          float a = (c[2*i]  -m)*rs*g3[cbase+2*i]   + b3[cbase+2*i];
          float d = (c[2*i+1]-m)*rs*g3[cbase+2*i+1] + b3[cbase+2*i+1];
          row[i] = pack2(a, d);
        }
      }
    }
  }

  const int wvM = tid >> 6, ln = tid & 63;
  const int colv = ln & 15, rgrp = ln >> 4;
  const int arow = ln & 15;
  const int aoy = wvM*2 + (arow >> 3), aox = arow & 7;

  f32x4 acc[6];
  #pragma unroll
  for (int j = 0; j < 6; j++) acc[j] = (f32x4){0.f,0.f,0.f,0.f};

  for (int tap = 0; tap < 9; tap++){
    const int ky = tap/3, kx = tap - (tap/3)*3;
    __syncthreads();
    if (wpk){
      const u32* wsrc = wpk + tap*4608;
      for (int e = tid; e < 4608; e += 256) wfr[e] = wsrc[e];
    } else {
      for (int e = tid; e < 4608; e += 256){
        int jk = e >> 8, lane = (e >> 2) & 63, q = e & 3;
        int j = jk/3, ks = jk - j*3;
        int n = j*16 + (lane & 15);
        int k = ks*32 + (lane >> 4)*8 + 2*q;
        wfr[e] = pack2(wOIHW[(n*96 + k)*9 + tap], wOIHW[(n*96 + k + 1)*9 + tap]);
      }
    }
    __syncthreads();
    const int p_in = (aoy + ky*DIL)*SX + aox + kx*DIL;
    bf16x8 af[3];
    #pragma unroll
    for (int ks = 0; ks < 3; ks++)
      af[ks] = *(const bf16x8*)&inT[p_in*104 + ks*32 + rgrp*8];
    #pragma unroll
    for (int j = 0; j < 6; j++){
      #pragma unroll
      for (int ks = 0; ks < 3; ks++){
        bf16x8 bfv = *(const bf16x8*)((const u16*)wfr + ((j*3 + ks)*64 + ln)*8);
        acc[j] = __builtin_amdgcn_mfma_f32_16x16x32_bf16(af[ks], bfv, acc[j], 0, 0, 0);
      }
    }
  }

  #pragma unroll
  for (int j = 0; j < 6; j++){
    const int oc = j*16 + colv;
    const float sc = bng[oc]*rsqrtf(bnv[oc]+1e-5f);
    const float mm = bnm[oc], bb = bnb[oc], cbv = cb[oc];
    #pragma unroll
    for (int r = 0; r < 4; r++){
      const int rowm = rgrp*4 + r;
      const int gy = by + wvM*2 + (rowm >> 3), gx = bx + (rowm & 7);
      size_t idx = ((size_t)((b*224+gy)*224+gx))*96 + oc;
      float t = (acc[j][r] + cbv - mm)*sc + bb;
      float o = gelu(t);
      if (FINAL){
        ((float*)dstv)[idx] = o + resid[idx];
      } else {
        ((u16*)dstv)[idx] = f2bf(o);
      }
    }
  }
}

// ---------------------------------------------------------------------------
extern "C" void kernel_launch(void* const* d_in, const int* in_sizes, int n_in,
                              void* d_out, int out_size, void* d_ws, size_t ws_size,
                              hipStream_t stream)
{
  const float* x    = (const float*)d_in[0];
  const float* ndwi = (const float*)d_in[1];
  const float* n1g  = (const float*)d_in[2];
  const float* n1b  = (const float*)d_in[3];
  const float* qkvw = (const float*)d_in[4];
  const float* qkvb = (const float*)d_in[5];
  const float* projw= (const float*)d_in[6];
  const float* projb= (const float*)d_in[7];
  const float* rpbt = (const float*)d_in[8];
  const float* n2g  = (const float*)d_in[9];
  const float* n2b  = (const float*)d_in[10];
  const float* w1   = (const float*)d_in[11];
  const float* b1   = (const float*)d_in[12];
  const float* w2   = (const float*)d_in[13];
  const float* b2   = (const float*)d_in[14];
  const float* n3g  = (const float*)d_in[15];
  const float* n3b  = (const float*)d_in[16];
  const float* c1w  = (const float*)d_in[17];
  const float* c1b  = (const float*)d_in[18];
  const float* bn1g = (const float*)d_in[19];
  const float* bn1b = (const float*)d_in[20];
  const float* bn1m = (const float*)d_in[21];
  const float* bn1v = (const float*)d_in[22];
  const float* c2w  = (const float*)d_in[23];
  const float* c2b  = (const float*)d_in[24];
  const float* bn2g = (const float*)d_in[25];
  const float* bn2b = (const float*)d_in[26];
  const float* bn2m = (const float*)d_in[27];
  const float* bn2v = (const float*)d_in[28];

  int B = out_size / (224*224*96);
  if (B < 1 || B > 64) B = 4;
  const size_t elems = (size_t)B*224*224*96;

  u16*   wsA = (u16*)d_ws;
  u32*   w8q = (u32*)d_out;
  u32*   w8p = w8q + 13824;
  float* xo  = (float*)d_out;
  u32*   wcv = nullptr;
  if (ws_size >= elems*sizeof(u16) + 82944*sizeof(u32))
    wcv = (u32*)(wsA + elems);

  wprep_k<<<dim3(72), dim3(256), 0, stream>>>(qkvw, projw, w8q, w8p);
  if (wcv) wprep_cv<<<dim3(324), dim3(256), 0, stream>>>(c1w, c2w, wcv);
  attn_k<<<dim3(B*1024), dim3(256), 0, stream>>>(x, ndwi, n1g, n1b, w8q, qkvb, w8p, projb, rpbt, wsA);
  mlp_k<<<dim3(B*784), dim3(256), 0, stream>>>(wsA, w1, b1, w2, b2, n2g, n2b, xo);
  convm_k<1,true ,false><<<dim3(28,28,B), dim3(256), 0, stream>>>(
      xo,  wcv,               c1w, c1b, bn1g, bn1b, bn1m, bn1v, n3g, n3b, nullptr, wsA);
  convm_k<2,false,true ><<<dim3(28,28,B), dim3(256), 0, stream>>>(
      wsA, wcv ? wcv+41472 : nullptr, c2w, c2b, bn2g, bn2b, bn2m, bn2v, nullptr, nullptr, xo, xo);
}

// Round 16
// 555.904 us; speedup vs baseline: 2.8616x; 1.1403x over previous
//
#include <hip/hip_runtime.h>
#include <hip/hip_bf16.h>

typedef unsigned int u32;
typedef unsigned short u16;

#define DF __device__ __forceinline__

DF float bf2f(u16 v){ u32 t = ((u32)v)<<16; return __builtin_bit_cast(float, t); }
DF u16 f2bf(float f){
  u32 t = __builtin_bit_cast(u32, f);
  t += 0x7fffu + ((t>>16)&1u);
  return (u16)(t>>16);
}
DF float lo16(u32 p){ return __builtin_bit_cast(float, p<<16); }
DF float hi16(u32 p){ return __builtin_bit_cast(float, p & 0xffff0000u); }
DF u32 pack2(float a, float b){ return (u32)f2bf(a) | (((u32)f2bf(b))<<16); }
DF float gelu(float x){ return 0.5f*x*(1.0f+erff(x*0.70710678118654752f)); }

#if defined(__has_builtin)
#if __has_builtin(__builtin_amdgcn_fdot2_f32_bf16)
#define HAVE_DOT2 1
#endif
#endif
#ifdef HAVE_DOT2
DF float dot2bf(u32 a, u32 b, float c){
  typedef __bf16 b2 __attribute__((ext_vector_type(2)));
  return __builtin_amdgcn_fdot2_f32_bf16(__builtin_bit_cast(b2,a), __builtin_bit_cast(b2,b), c, false);
}
#else
DF float dot2bf(u32 a, u32 b, float c){
  float d;
  asm("v_dot2_f32_bf16 %0, %1, %2, %3" : "=v"(d) : "v"(a), "v"(b), "v"(c));
  return d;
}
#endif

typedef __attribute__((ext_vector_type(8))) __bf16 bf16x8;
typedef __attribute__((ext_vector_type(4))) float f32x4;

// ---------------------------------------------------------------------------
// K0: pack qkv/proj weights as MFMA B-fragments (front of d_out).
// ---------------------------------------------------------------------------
__global__ void wprep_k(const float* __restrict__ qkvw, const float* __restrict__ projw,
                        u32* __restrict__ w8q, u32* __restrict__ w8p)
{
  int e = blockIdx.x*256 + threadIdx.x;
  if (e < 13824){
    int jk = e >> 8, lane = (e >> 2) & 63, q = e & 3;
    int jt = jk/3, ks = jk - jt*3;
    int n = jt*16 + (lane & 15);
    int k = ks*32 + (lane >> 4)*8 + 2*q;
    w8q[e] = pack2(qkvw[n*96 + k], qkvw[n*96 + k + 1]);
  } else if (e < 18432){
    int r2 = e - 13824;
    int jk = r2 >> 8, lane = (r2 >> 2) & 63, q = r2 & 3;
    int jt = jk/3, ks = jk - jt*3;
    int n = jt*16 + (lane & 15);
    int k = ks*32 + (lane >> 4)*8 + 2*q;
    w8p[r2] = pack2(projw[n*96 + k], projw[n*96 + k + 1]);
  }
}

// ---------------------------------------------------------------------------
// K0b: conv weights as MFMA B-fragments into ws tail.
// ---------------------------------------------------------------------------
__global__ void wprep_cv(const float* __restrict__ c1w, const float* __restrict__ c2w,
                         u32* __restrict__ wcv)
{
  int e = blockIdx.x*256 + threadIdx.x;
  if (e >= 82944) return;
  int conv = e / 41472, r = e - conv*41472;
  int tap = r / 4608, r2 = r - tap*4608;
  int jk = r2 >> 8;
  int lane = (r2 >> 2) & 63;
  int q = r2 & 3;
  int j = jk/3, ks = jk - j*3;
  int n = j*16 + (lane & 15);
  int k = ks*32 + (lane >> 4)*8 + 2*q;
  const float* s = conv ? c2w : c1w;
  wcv[e] = pack2(s[(n*96 + k)*9 + tap], s[(n*96 + k + 1)*9 + tap]);
}

// ---------------------------------------------------------------------------
// K0c: mlp w1/w2 as MFMA B-fragments into ws tail (after wcv).
// w1m: [q(4)][jt(6)][ks(3)][lane][4]  (18432 u32); w2m likewise after.
// ---------------------------------------------------------------------------
__global__ void wprep_m(const float* __restrict__ w1, const float* __restrict__ w2,
                        u32* __restrict__ wm)
{
  int e = blockIdx.x*256 + threadIdx.x;
  if (e >= 36864) return;
  int which = e / 18432, r = e - which*18432;
  int q = r / 4608, r2 = r - q*4608;
  int jk = r2 >> 8, lane = (r2 >> 2) & 63, qq = r2 & 3;
  int jt = jk/3, ks = jk - jt*3;
  int n = jt*16 + (lane & 15);
  int k = ks*32 + (lane >> 4)*8 + 2*qq;
  if (which == 0){
    const float* s = w1 + (size_t)(q*96 + n)*96 + k;   // [hidden][c]
    wm[e] = pack2(s[0], s[1]);
  } else {
    const float* s = w2 + (size_t)n*384 + q*96 + k;    // [oc][hidden]
    wm[e] = pack2(s[0], s[1]);
  }
}

// ---------------------------------------------------------------------------
// K1: fused windowed attention (unchanged from R15; 232us verified).
// ---------------------------------------------------------------------------
__global__ __launch_bounds__(256,3) void attn_k(
    const float* __restrict__ x, const float* __restrict__ ndwi,
    const float* __restrict__ n1g, const float* __restrict__ n1b,
    const u32* __restrict__ w8q, const float* __restrict__ qb,
    const u32* __restrict__ w8p, const float* __restrict__ pb,
    const float* __restrict__ rpbt, u16* __restrict__ x1o)
{
  __shared__ __align__(16) u16 xA[4*3*64*8];
  __shared__ u32 qp[49*49];
  __shared__ u32 kp[49*49];
  __shared__ u16 vpT[96*50];
  __shared__ float rpb[8*169];
  __shared__ float mw[49];
  const int tid = threadIdx.x;
  const int blk = blockIdx.x;
  const int b = blk >> 10, wy = (blk>>5)&31, wx = blk&31;
  const int wv_ = __builtin_amdgcn_readfirstlane(tid >> 6);
  const int ln  = tid & 63;
  const int colv = ln & 15, rgrp = ln >> 4;

  for (int i = tid; i < 1352; i += 256){
    int h = i/169, idx = i - h*169;
    rpb[i] = rpbt[idx*8 + h];
  }
  for (int i = tid; i < 96; i += 256) vpT[i*50 + 49] = 0;

  if (tid < 196){
    const int t = tid >> 2, p = tid & 3;
    const int ty = t/7, tx = t - (t/7)*7;
    int sy = wy*7 + ty - 3; if (sy < 0) sy += 224;
    int sx = wx*7 + tx - 3; if (sx < 0) sx += 224;
    const size_t rowb = ((size_t)((b*224 + sy)*224 + sx))*96;
    const float* xr = x + rowb + p*24;
    float c[24];
    #pragma unroll
    for (int q = 0; q < 6; q++){
      float4 v = ((const float4*)xr)[q];
      c[q*4+0]=v.x; c[q*4+1]=v.y; c[q*4+2]=v.z; c[q*4+3]=v.w;
    }
    if (p == 0) mw[t] = ndwi[(size_t)b*50176 + sy*224 + sx];
    float s = 0.f, s2 = 0.f;
    #pragma unroll
    for (int j = 0; j < 24; j++){ s += c[j]; s2 += c[j]*c[j]; }
    s  += __shfl_xor(s, 1);  s  += __shfl_xor(s, 2);
    s2 += __shfl_xor(s2, 1); s2 += __shfl_xor(s2, 2);
    float m = s*(1.f/96.f);
    float rs = rsqrtf(s2*(1.f/96.f) - m*m + 1e-5f);
    const int mt = t >> 4, row = t & 15;
    #pragma unroll
    for (int jj = 0; jj < 12; jj++){
      int k = p*24 + 2*jj;
      float a = (c[2*jj]  -m)*rs*n1g[k]   + n1b[k];
      float d = (c[2*jj+1]-m)*rs*n1g[k+1] + n1b[k+1];
      int ks = k >> 5, g = (k & 31) >> 3, i = k & 7;
      *(u32*)&xA[(((mt*3 + ks)*64 + g*16 + row)<<3) + i] = pack2(a, d);
    }
  }
  __syncthreads();

  {
    bf16x8 af[3];
    #pragma unroll
    for (int ks = 0; ks < 3; ks++)
      af[ks] = *(const bf16x8*)&xA[((wv_*3 + ks)*64 + ln)*8];
    u16* qpu = (u16*)qp;
    u16* kpu = (u16*)kp;
    const float S = 0.28867513459481287f;
    for (int jt = 0; jt < 18; jt++){
      f32x4 c = (f32x4){0.f,0.f,0.f,0.f};
      #pragma unroll
      for (int ks = 0; ks < 3; ks++){
        bf16x8 bw = *(const bf16x8*)(w8q + ((jt*3 + ks)*64 + ln)*4);
        c = __builtin_amdgcn_mfma_f32_16x16x32_bf16(af[ks], bw, c, 0, 0, 0);
      }
      const int oc = jt*16 + colv;
      const float bv = qb[oc];
      #pragma unroll
      for (int r = 0; r < 4; r++){
        int tok = wv_*16 + rgrp*4 + r;
        if (tok < 49){
          float v = c[r] + bv;
          if (oc < 96)       qpu[tok*98 + oc]        = f2bf(v*S);
          else if (oc < 192) kpu[tok*98 + (oc-96)]   = f2bf(v);
          else               vpT[(oc-192)*50 + tok]  = f2bf(v);
        }
      }
    }
  }
  __syncthreads();

  for (int task = tid; task < 392; task += 256){
    int h = task/49, i = task - (task/49)*49;
    int iy = i/7, ix = i - (i/7)*7;
    u32 qv[6];
    #pragma unroll
    for (int e = 0; e < 6; e++) qv[e] = qp[i*49 + h*6 + e];
    const float* rb = &rpb[h*169 + (iy+6)*13 + (ix+6)];
    float s[49]; float mx = -1e30f;
    float mi = mw[i];
    int j = 0;
    #pragma unroll
    for (int jy = 0; jy < 7; jy++)
    #pragma unroll
    for (int jx = 0; jx < 7; jx++, j++){
      const u32* kr = &kp[j*49 + h*6];
      float a = rb[-(jy*13+jx)];
      a = dot2bf(qv[0], kr[0], a); a = dot2bf(qv[1], kr[1], a);
      a = dot2bf(qv[2], kr[2], a); a = dot2bf(qv[3], kr[3], a);
      a = dot2bf(qv[4], kr[4], a); a = dot2bf(qv[5], kr[5], a);
      a = (mi != mw[j]) ? a - 100.f : a;
      s[j] = a; mx = fmaxf(mx, a);
    }
    float l = 0.f;
    #pragma unroll
    for (int jj = 0; jj < 49; jj++){ float p = __expf(s[jj]-mx); s[jj] = p; l += p; }
    float rl = 1.f/l;
    u32 pp[25];
    #pragma unroll
    for (int e = 0; e < 24; e++)
      pp[e] = (__builtin_bit_cast(u32, s[2*e]) >> 16)
            | (__builtin_bit_cast(u32, s[2*e+1]) & 0xffff0000u);
    pp[24] = __builtin_bit_cast(u32, s[48]) >> 16;
    float o[12];
    #pragma unroll
    for (int d = 0; d < 12; d++){
      const u32* vr = (const u32*)(vpT + (h*12+d)*50);
      float od = 0.f;
      #pragma unroll
      for (int e = 0; e < 25; e++) od = dot2bf(pp[e], vr[e], od);
      o[d] = od*rl;
    }
    const int mt2 = i >> 4, row2 = i & 15;
    #pragma unroll
    for (int m = 0; m < 6; m++){
      int k = h*12 + 2*m;
      int ks = k >> 5, g = (k & 31) >> 3, ii = k & 7;
      *(u32*)&xA[(((mt2*3 + ks)*64 + g*16 + row2)<<3) + ii] = pack2(o[2*m], o[2*m+1]);
    }
  }
  __syncthreads();

  {
    bf16x8 af[3];
    #pragma unroll
    for (int ks = 0; ks < 3; ks++)
      af[ks] = *(const bf16x8*)&xA[((wv_*3 + ks)*64 + ln)*8];
    u16* qpu = (u16*)qp;
    for (int jt = 0; jt < 6; jt++){
      f32x4 c = (f32x4){0.f,0.f,0.f,0.f};
      #pragma unroll
      for (int ks = 0; ks < 3; ks++){
        bf16x8 bw = *(const bf16x8*)(w8p + ((jt*3 + ks)*64 + ln)*4);
        c = __builtin_amdgcn_mfma_f32_16x16x32_bf16(af[ks], bw, c, 0, 0, 0);
      }
      const int oc = jt*16 + colv;
      const float bv = pb[oc];
      #pragma unroll
      for (int r = 0; r < 4; r++){
        int tok = wv_*16 + rgrp*4 + r;
        if (tok < 49) qpu[tok*98 + oc] = f2bf(c[r] + bv);
      }
    }
  }
  __syncthreads();

  for (int e = tid; e < 588; e += 256){
    int t = e/12, g = e - (e/12)*12;
    int ty = t/7, tx = t - (t/7)*7;
    int dy = wy*7 + ty - 4; if (dy < 0) dy += 224;
    int dx = wx*7 + tx - 4; if (dx < 0) dx += 224;
    size_t base = ((size_t)((b*224+dy)*224+dx))*96 + g*8;
    float4 r0 = *(const float4*)(x + base);
    float4 r1 = *(const float4*)(x + base + 4);
    const u32* pr = &qp[t*49 + g*4];
    uint4 ov;
    ov.x = pack2(lo16(pr[0])+r0.x, hi16(pr[0])+r0.y);
    ov.y = pack2(lo16(pr[1])+r0.z, hi16(pr[1])+r0.w);
    ov.z = pack2(lo16(pr[2])+r1.x, hi16(pr[2])+r1.y);
    ov.w = pack2(lo16(pr[3])+r1.z, hi16(pr[3])+r1.w);
    *(uint4*)(x1o + base) = ov;
  }
}

// ---------------------------------------------------------------------------
// K2a: MLP, B-fragments DIRECT from global (wm). xA/hA wave-private.
// LDS 24KB -> 4 blocks/CU.
// ---------------------------------------------------------------------------
__global__ __launch_bounds__(256,4) void mlp_direct_k(
    const u16* __restrict__ x1, const u32* __restrict__ wm,
    const float* __restrict__ b1, const float* __restrict__ b2,
    const float* __restrict__ g2, const float* __restrict__ bb2,
    float* __restrict__ x2o)
{
  __shared__ __align__(16) u16 xA[4*3*64*8];   // 12KB
  __shared__ __align__(16) u16 hA[4*3*64*8];   // 12KB
  const int tid = threadIdx.x;
  const size_t t0 = (size_t)blockIdx.x * 64;
  const int wvM = tid >> 6;
  const int ln  = tid & 63;
  const int colv = ln & 15, rgrp = ln >> 4;
  const u32* w1m = wm;
  const u32* w2m = wm + 18432;

  {
    const int t = tid >> 2, p = tid & 3;
    const u16* xr = x1 + (t0 + t)*96 + p*24;
    float c[24];
    #pragma unroll
    for (int q = 0; q < 3; q++){
      uint4 v = ((const uint4*)xr)[q];
      c[q*8+0]=lo16(v.x); c[q*8+1]=hi16(v.x);
      c[q*8+2]=lo16(v.y); c[q*8+3]=hi16(v.y);
      c[q*8+4]=lo16(v.z); c[q*8+5]=hi16(v.z);
      c[q*8+6]=lo16(v.w); c[q*8+7]=hi16(v.w);
    }
    float s = 0.f, s2 = 0.f;
    #pragma unroll
    for (int j = 0; j < 24; j++){ s += c[j]; s2 += c[j]*c[j]; }
    s  += __shfl_xor(s, 1);  s  += __shfl_xor(s, 2);
    s2 += __shfl_xor(s2, 1); s2 += __shfl_xor(s2, 2);
    float m = s*(1.f/96.f);
    float rs = rsqrtf(s2*(1.f/96.f) - m*m + 1e-5f);
    const int mt = t >> 4, row = t & 15;
    #pragma unroll
    for (int jj = 0; jj < 12; jj++){
      int k = p*24 + 2*jj;
      float a = (c[2*jj]  -m)*rs*g2[k]   + bb2[k];
      float d = (c[2*jj+1]-m)*rs*g2[k+1] + bb2[k+1];
      int ks = k >> 5, g = (k & 31) >> 3, i = k & 7;
      *(u32*)&xA[(((mt*3 + ks)*64 + g*16 + row)<<3) + i] = pack2(a, d);
    }
  }
  __syncthreads();

  bf16x8 af[3];
  #pragma unroll
  for (int ks = 0; ks < 3; ks++)
    af[ks] = *(const bf16x8*)&xA[((wvM*3 + ks)*64 + ln)*8];

  f32x4 acc2[6];
  #pragma unroll
  for (int j = 0; j < 6; j++) acc2[j] = (f32x4){0.f,0.f,0.f,0.f};

  for (int q = 0; q < 4; q++){
    __syncthreads();
    #pragma unroll
    for (int j = 0; j < 6; j++){
      f32x4 c = (f32x4){0.f,0.f,0.f,0.f};
      #pragma unroll
      for (int ks = 0; ks < 3; ks++){
        bf16x8 bfv = *(const bf16x8*)(w1m + ((q*18 + j*3 + ks)*64 + ln)*4);
        c = __builtin_amdgcn_mfma_f32_16x16x32_bf16(af[ks], bfv, c, 0, 0, 0);
      }
      const float bv = b1[q*96 + j*16 + colv];
      const int kq = j*16 + colv;
      const int ks2 = kq >> 5, gg = (kq & 31) >> 3, ii = kq & 7;
      u16* hdst = &hA[(((wvM*3 + ks2)*64 + gg*16)<<3) + ii];
      #pragma unroll
      for (int r = 0; r < 4; r++){
        int rowh = rgrp*4 + r;
        hdst[rowh*8] = f2bf(gelu(c[r] + bv));
      }
    }
    __syncthreads();

    bf16x8 hf[3];
    #pragma unroll
    for (int ks = 0; ks < 3; ks++)
      hf[ks] = *(const bf16x8*)&hA[((wvM*3 + ks)*64 + ln)*8];
    #pragma unroll
    for (int j = 0; j < 6; j++){
      #pragma unroll
      for (int ks = 0; ks < 3; ks++){
        bf16x8 bfv = *(const bf16x8*)(w2m + ((q*18 + j*3 + ks)*64 + ln)*4);
        acc2[j] = __builtin_amdgcn_mfma_f32_16x16x32_bf16(hf[ks], bfv, acc2[j], 0, 0, 0);
      }
    }
  }

  #pragma unroll
  for (int j = 0; j < 6; j++){
    const int oc = j*16 + colv;
    const float bv = b2[oc];
    #pragma unroll
    for (int r = 0; r < 4; r++){
      size_t tok = t0 + wvM*16 + rgrp*4 + r;
      x2o[tok*96 + oc] = acc2[j][r] + bv + bf2f(x1[tok*96 + oc]);
    }
  }
}

// ---------------------------------------------------------------------------
// K2b: MLP, staged fallback (R15-verified).
// ---------------------------------------------------------------------------
__global__ __launch_bounds__(256,2) void mlp_stage_k(
    const u16* __restrict__ x1, const float* __restrict__ w1, const float* __restrict__ b1,
    const float* __restrict__ w2, const float* __restrict__ b2,
    const float* __restrict__ g2, const float* __restrict__ bb2,
    float* __restrict__ x2o)
{
  __shared__ __align__(16) u16 xA [4*3*64*8];
  __shared__ __align__(16) u16 hA [4*3*64*8];
  __shared__ __align__(16) u16 w1f[6*3*64*8];
  __shared__ __align__(16) u16 w2f[6*3*64*8];
  const int tid = threadIdx.x;
  const size_t t0 = (size_t)blockIdx.x * 64;
  const int wvM = tid >> 6;
  const int ln  = tid & 63;
  const int colv = ln & 15, rgrp = ln >> 4;

  {
    const int t = tid >> 2, p = tid & 3;
    const u16* xr = x1 + (t0 + t)*96 + p*24;
    float c[24];
    #pragma unroll
    for (int q = 0; q < 3; q++){
      uint4 v = ((const uint4*)xr)[q];
      c[q*8+0]=lo16(v.x); c[q*8+1]=hi16(v.x);
      c[q*8+2]=lo16(v.y); c[q*8+3]=hi16(v.y);
      c[q*8+4]=lo16(v.z); c[q*8+5]=hi16(v.z);
      c[q*8+6]=lo16(v.w); c[q*8+7]=hi16(v.w);
    }
    float s = 0.f, s2 = 0.f;
    #pragma unroll
    for (int j = 0; j < 24; j++){ s += c[j]; s2 += c[j]*c[j]; }
    s  += __shfl_xor(s, 1);  s  += __shfl_xor(s, 2);
    s2 += __shfl_xor(s2, 1); s2 += __shfl_xor(s2, 2);
    float m = s*(1.f/96.f);
    float rs = rsqrtf(s2*(1.f/96.f) - m*m + 1e-5f);
    const int mt = t >> 4, row = t & 15;
    #pragma unroll
    for (int jj = 0; jj < 12; jj++){
      int k = p*24 + 2*jj;
      float a = (c[2*jj]  -m)*rs*g2[k]   + bb2[k];
      float d = (c[2*jj+1]-m)*rs*g2[k+1] + bb2[k+1];
      int ks = k >> 5, g = (k & 31) >> 3, i = k & 7;
      *(u32*)&xA[(((mt*3 + ks)*64 + g*16 + row)<<3) + i] = pack2(a, d);
    }
  }

  f32x4 acc2[6];
  #pragma unroll
  for (int j = 0; j < 6; j++) acc2[j] = (f32x4){0.f,0.f,0.f,0.f};

  for (int q = 0; q < 4; q++){
    __syncthreads();
    for (int e = tid; e < 4608; e += 256){
      int n = e/48, cp = e - (e/48)*48, k = cp*2;
      int ks = k >> 5, g = (k & 31) >> 3, i = k & 7;
      int fidx = ((((n>>4)*3 + ks)*64 + g*16 + (n&15))<<3) + i;
      {
        const float* s = w1 + (size_t)(q*96 + n)*96 + k;
        *(u32*)&w1f[fidx] = pack2(s[0], s[1]);
      }
      {
        const float* s = w2 + (size_t)n*384 + q*96 + k;
        *(u32*)&w2f[fidx] = pack2(s[0], s[1]);
      }
    }
    __syncthreads();

    bf16x8 af[3];
    #pragma unroll
    for (int ks = 0; ks < 3; ks++)
      af[ks] = *(const bf16x8*)&xA[((wvM*3 + ks)*64 + ln)*8];
    #pragma unroll
    for (int j = 0; j < 6; j++){
      f32x4 c = (f32x4){0.f,0.f,0.f,0.f};
      #pragma unroll
      for (int ks = 0; ks < 3; ks++){
        bf16x8 bfv = *(const bf16x8*)&w1f[((j*3 + ks)*64 + ln)*8];
        c = __builtin_amdgcn_mfma_f32_16x16x32_bf16(af[ks], bfv, c, 0, 0, 0);
      }
      const float bv = b1[q*96 + j*16 + colv];
      const int kq = j*16 + colv;
      const int ks2 = kq >> 5, gg = (kq & 31) >> 3, ii = kq & 7;
      u16* hdst = &hA[(((wvM*3 + ks2)*64 + gg*16)<<3) + ii];
      #pragma unroll
      for (int r = 0; r < 4; r++){
        int rowh = rgrp*4 + r;
        hdst[rowh*8] = f2bf(gelu(c[r] + bv));
      }
    }
    __syncthreads();

    bf16x8 hf[3];
    #pragma unroll
    for (int ks = 0; ks < 3; ks++)
      hf[ks] = *(const bf16x8*)&hA[((wvM*3 + ks)*64 + ln)*8];
    #pragma unroll
    for (int j = 0; j < 6; j++){
      #pragma unroll
      for (int ks = 0; ks < 3; ks++){
        bf16x8 bfv = *(const bf16x8*)&w2f[((j*3 + ks)*64 + ln)*8];
        acc2[j] = __builtin_amdgcn_mfma_f32_16x16x32_bf16(hf[ks], bfv, acc2[j], 0, 0, 0);
      }
    }
  }

  #pragma unroll
  for (int j = 0; j < 6; j++){
    const int oc = j*16 + colv;
    const float bv = b2[oc];
    #pragma unroll
    for (int r = 0; r < 4; r++){
      size_t tok = t0 + wvM*16 + rgrp*4 + r;
      x2o[tok*96 + oc] = acc2[j][r] + bv + bf2f(x1[tok*96 + oc]);
    }
  }
}

// ---------------------------------------------------------------------------
// K3: MFMA implicit-GEMM 3x3 conv. WD: B-frags direct from global, no tap
// barriers. Fallback: per-tap LDS staging (R14-verified).
// ---------------------------------------------------------------------------
template<int DIL, bool LN3, bool FINAL, bool WD>
__global__ __launch_bounds__(256,4) void convm_k(
    const void* __restrict__ srcv, const u32* __restrict__ wpk,
    const float* __restrict__ wOIHW,
    const float* __restrict__ cb, const float* __restrict__ bng, const float* __restrict__ bnb,
    const float* __restrict__ bnm, const float* __restrict__ bnv,
    const float* __restrict__ g3, const float* __restrict__ b3,
    const float* resid, void* dstv)
{
  constexpr int SY = 8 + 2*DIL, SX = 8 + 2*DIL, NPIX = SY*SX;
  __shared__ __align__(16) u16 inT[NPIX*104];
  const int tid = threadIdx.x;
  const int bx = blockIdx.x*8, by = blockIdx.y*8, b = blockIdx.z;
  const int gy0 = by - DIL, gx0 = bx - DIL;

  for (int e = tid; e < NPIX*48; e += 256){
    int p = e/48, c2 = e - (e/48)*48;
    int y = p/SX, xx = p - (p/SX)*SX;
    int gy = gy0+y, gx = gx0+xx;
    u32 v = 0;
    if (gy >= 0 && gy < 224 && gx >= 0 && gx < 224){
      size_t idx = ((size_t)((b*224+gy)*224+gx))*96 + c2*2;
      if (LN3){
        float2 rd = *(const float2*)((const float*)srcv + idx);
        v = pack2(rd.x, rd.y);
      } else {
        v = *(const u32*)((const u16*)srcv + idx);
      }
    }
    *(u32*)&inT[p*104 + c2*2] = v;
  }
  __syncthreads();
  if (LN3){
    if (tid < 2*NPIX){
      const int p = tid >> 1, half = tid & 1;
      int y = p/SX, xx = p - (p/SX)*SX;
      int gy = gy0+y, gx = gx0+xx;
      if (gy >= 0 && gy < 224 && gx >= 0 && gx < 224){
        u32* row = (u32*)&inT[p*104] + half*24;
        float c[48];
        #pragma unroll
        for (int i = 0; i < 24; i++){ u32 v = row[i]; c[2*i] = lo16(v); c[2*i+1] = hi16(v); }
        float s = 0.f, s2 = 0.f;
        #pragma unroll
        for (int i = 0; i < 48; i++){ s += c[i]; s2 += c[i]*c[i]; }
        s  += __shfl_xor(s, 1);
        s2 += __shfl_xor(s2, 1);
        float m = s*(1.f/96.f);
        float rs = rsqrtf(s2*(1.f/96.f) - m*m + 1e-5f);
        const int cbase = half*48;
        #pragma unroll
        for (int i = 0; i < 24; i++){
          float a = (c[2*i]  -m)*rs*g3[cbase+2*i]   + b3[cbase+2*i];
          float d = (c[2*i+1]-m)*rs*g3[cbase+2*i+1] + b3[cbase+2*i+1];
          row[i] = pack2(a, d);
        }
      }
    }
    __syncthreads();
  }

  const int wvM = tid >> 6, ln = tid & 63;
  const int colv = ln & 15, rgrp = ln >> 4;
  const int arow = ln & 15;
  const int aoy = wvM*2 + (arow >> 3), aox = arow & 7;

  f32x4 acc[6];
  #pragma unroll
  for (int j = 0; j < 6; j++) acc[j] = (f32x4){0.f,0.f,0.f,0.f};

  if constexpr (WD){
    // barrier-free tap loop; B-fragments straight from L2-resident global
    #pragma unroll 3
    for (int tap = 0; tap < 9; tap++){
      const int ky = tap/3, kx = tap - (tap/3)*3;
      const int p_in = (aoy + ky*DIL)*SX + aox + kx*DIL;
      bf16x8 af[3];
      #pragma unroll
      for (int ks = 0; ks < 3; ks++)
        af[ks] = *(const bf16x8*)&inT[p_in*104 + ks*32 + rgrp*8];
      const u32* wt = wpk + tap*4608;
      #pragma unroll
      for (int j = 0; j < 6; j++){
        #pragma unroll
        for (int ks = 0; ks < 3; ks++){
          bf16x8 bfv = *(const bf16x8*)(wt + ((j*3 + ks)*64 + ln)*4);
          acc[j] = __builtin_amdgcn_mfma_f32_16x16x32_bf16(af[ks], bfv, acc[j], 0, 0, 0);
        }
      }
    }
  } else {
    __shared__ __align__(16) u32 wfr[4608];
    for (int tap = 0; tap < 9; tap++){
      const int ky = tap/3, kx = tap - (tap/3)*3;
      __syncthreads();
      for (int e = tid; e < 4608; e += 256){
        int jk = e >> 8, lane = (e >> 2) & 63, q = e & 3;
        int j = jk/3, ks = jk - j*3;
        int n = j*16 + (lane & 15);
        int k = ks*32 + (lane >> 4)*8 + 2*q;
        wfr[e] = pack2(wOIHW[(n*96 + k)*9 + tap], wOIHW[(n*96 + k + 1)*9 + tap]);
      }
      __syncthreads();
      const int p_in = (aoy + ky*DIL)*SX + aox + kx*DIL;
      bf16x8 af[3];
      #pragma unroll
      for (int ks = 0; ks < 3; ks++)
        af[ks] = *(const bf16x8*)&inT[p_in*104 + ks*32 + rgrp*8];
      #pragma unroll
      for (int j = 0; j < 6; j++){
        #pragma unroll
        for (int ks = 0; ks < 3; ks++){
          bf16x8 bfv = *(const bf16x8*)((const u16*)wfr + ((j*3 + ks)*64 + ln)*8);
          acc[j] = __builtin_amdgcn_mfma_f32_16x16x32_bf16(af[ks], bfv, acc[j], 0, 0, 0);
        }
      }
    }
  }

  #pragma unroll
  for (int j = 0; j < 6; j++){
    const int oc = j*16 + colv;
    const float sc = bng[oc]*rsqrtf(bnv[oc]+1e-5f);
    const float mm = bnm[oc], bb = bnb[oc], cbv = cb[oc];
    #pragma unroll
    for (int r = 0; r < 4; r++){
      const int rowm = rgrp*4 + r;
      const int gy = by + wvM*2 + (rowm >> 3), gx = bx + (rowm & 7);
      size_t idx = ((size_t)((b*224+gy)*224+gx))*96 + oc;
      float t = (acc[j][r] + cbv - mm)*sc + bb;
      float o = gelu(t);
      if (FINAL){
        ((float*)dstv)[idx] = o + resid[idx];
      } else {
        ((u16*)dstv)[idx] = f2bf(o);
      }
    }
  }
}

// ---------------------------------------------------------------------------
extern "C" void kernel_launch(void* const* d_in, const int* in_sizes, int n_in,
                              void* d_out, int out_size, void* d_ws, size_t ws_size,
                              hipStream_t stream)
{
  const float* x    = (const float*)d_in[0];
  const float* ndwi = (const float*)d_in[1];
  const float* n1g  = (const float*)d_in[2];
  const float* n1b  = (const float*)d_in[3];
  const float* qkvw = (const float*)d_in[4];
  const float* qkvb = (const float*)d_in[5];
  const float* projw= (const float*)d_in[6];
  const float* projb= (const float*)d_in[7];
  const float* rpbt = (const float*)d_in[8];
  const float* n2g  = (const float*)d_in[9];
  const float* n2b  = (const float*)d_in[10];
  const float* w1   = (const float*)d_in[11];
  const float* b1   = (const float*)d_in[12];
  const float* w2   = (const float*)d_in[13];
  const float* b2   = (const float*)d_in[14];
  const float* n3g  = (const float*)d_in[15];
  const float* n3b  = (const float*)d_in[16];
  const float* c1w  = (const float*)d_in[17];
  const float* c1b  = (const float*)d_in[18];
  const float* bn1g = (const float*)d_in[19];
  const float* bn1b = (const float*)d_in[20];
  const float* bn1m = (const float*)d_in[21];
  const float* bn1v = (const float*)d_in[22];
  const float* c2w  = (const float*)d_in[23];
  const float* c2b  = (const float*)d_in[24];
  const float* bn2g = (const float*)d_in[25];
  const float* bn2b = (const float*)d_in[26];
  const float* bn2m = (const float*)d_in[27];
  const float* bn2v = (const float*)d_in[28];

  int B = out_size / (224*224*96);
  if (B < 1 || B > 64) B = 4;
  const size_t elems = (size_t)B*224*224*96;

  u16*   wsA = (u16*)d_ws;
  u32*   w8q = (u32*)d_out;
  u32*   w8p = w8q + 13824;
  float* xo  = (float*)d_out;
  u32*   wcv = nullptr;
  u32*   wm  = nullptr;
  if (ws_size >= elems*sizeof(u16) + 82944*sizeof(u32))
    wcv = (u32*)(wsA + elems);
  if (ws_size >= elems*sizeof(u16) + (82944 + 36864)*sizeof(u32))
    wm = wcv + 82944;

  wprep_k<<<dim3(72), dim3(256), 0, stream>>>(qkvw, projw, w8q, w8p);
  if (wcv) wprep_cv<<<dim3(324), dim3(256), 0, stream>>>(c1w, c2w, wcv);
  if (wm)  wprep_m<<<dim3(144), dim3(256), 0, stream>>>(w1, w2, wm);
  attn_k<<<dim3(B*1024), dim3(256), 0, stream>>>(x, ndwi, n1g, n1b, w8q, qkvb, w8p, projb, rpbt, wsA);
  if (wm)
    mlp_direct_k<<<dim3(B*784), dim3(256), 0, stream>>>(wsA, wm, b1, b2, n2g, n2b, xo);
  else
    mlp_stage_k<<<dim3(B*784), dim3(256), 0, stream>>>(wsA, w1, b1, w2, b2, n2g, n2b, xo);
  if (wcv){
    convm_k<1,true ,false,true ><<<dim3(28,28,B), dim3(256), 0, stream>>>(
        xo,  wcv,        c1w, c1b, bn1g, bn1b, bn1m, bn1v, n3g, n3b, nullptr, wsA);
    convm_k<2,false,true ,true ><<<dim3(28,28,B), dim3(256), 0, stream>>>(
        wsA, wcv+41472,  c2w, c2b, bn2g, bn2b, bn2m, bn2v, nullptr, nullptr, xo, xo);
  } else {
    convm_k<1,true ,false,false><<<dim3(28,28,B), dim3(256), 0, stream>>>(
        xo,  nullptr,    c1w, c1b, bn1g, bn1b, bn1m, bn1v, n3g, n3b, nullptr, wsA);
    convm_k<2,false,true ,false><<<dim3(28,28,B), dim3(256), 0, stream>>>(
        wsA, nullptr,    c2w, c2b, bn2g, bn2b, bn2m, bn2v, nullptr, nullptr, xo, xo);
  }
}